// Round 1
// baseline (1381.232 us; speedup 1.0000x reference)
//
#include <hip/hip_runtime.h>
#include <cstdint>

#define NP 16384     // paths
#define NE 4096      // edges
#define DIM 128      // link/path dim
#define ML 20        // max len
#define TP 16        // paths per GRU tile
#define NT (NP/TP)   // 1024 tiles

// ---------------- sort / setup kernels ----------------

__global__ void k_zero_counts(int* counts) {
    if (threadIdx.x < 32) counts[threadIdx.x] = 0;
}

__global__ void k_hist(const int* __restrict__ lens, int* counts) {
    int p = blockIdx.x * 256 + threadIdx.x;
    if (p < NP) atomicAdd(&counts[lens[p]], 1);
}

__global__ void k_prefix(const int* __restrict__ counts, int* starts) {
    if (threadIdx.x == 0) {
        int s = 0;
        for (int i = 0; i <= ML; ++i) { starts[i] = s; s += counts[i]; }
    }
}

__global__ void k_perm(const int* __restrict__ lens, int* starts, int* perm) {
    int p = blockIdx.x * 256 + threadIdx.x;
    if (p < NP) {
        int pos = atomicAdd(&starts[lens[p]], 1);
        perm[pos] = p;  // order within a bin is nondeterministic; output is invariant
    }
}

__global__ void k_edge(const int* __restrict__ idx, const int* __restrict__ seqs,
                       const int* __restrict__ paths, int total, int* __restrict__ edge_map) {
    int i = blockIdx.x * 256 + threadIdx.x;
    if (i < total) edge_map[idx[i] * ML + seqs[i]] = paths[i];
}

// ---------------- GRU forward ----------------
// One wg (256 thr) processes paired tiles (b, NT-1-b) sequentially for load balance.
// Thread (d-pair, path-group-of-4): 32 f32 accumulators; x,h transposed in LDS
// (wave-uniform broadcast reads); weights streamed from L2, float2 per-lane coalesced.

__global__ __launch_bounds__(256, 2) void k_gru(
    const float* __restrict__ inputs, const int* __restrict__ lens,
    const float* __restrict__ gk, const float* __restrict__ gr,
    const float* __restrict__ gb, const int* __restrict__ edge_map,
    const int* __restrict__ perm, float* __restrict__ hs, float* __restrict__ last)
{
    __shared__ float HT[DIM][TP];   // h transposed: HT[d][p]
    __shared__ float XT[DIM][TP];   // x transposed
    __shared__ int pgs[TP];
    __shared__ int lns[TP];

    const int tid  = threadIdx.x;
    const int d0   = (tid & 63) * 2;   // this thread's d-pair
    const int p0   = (tid >> 6) * 4;   // 4 paths per thread

    // biases (b0 = gb[0..383], b1 = gb[384..767]); z,r parts can be pre-summed
    const float bz0 = gb[d0]       + gb[384 + d0];
    const float bz1 = gb[d0 + 1]   + gb[384 + d0 + 1];
    const float br0 = gb[128 + d0] + gb[512 + d0];
    const float br1 = gb[128 + d0 + 1] + gb[512 + d0 + 1];
    const float bx0 = gb[256 + d0],     bx1 = gb[256 + d0 + 1];
    const float bh0 = gb[640 + d0],     bh1 = gb[640 + d0 + 1];

    for (int half = 0; half < 2; ++half) {
        const int tile = half ? (NT - 1 - (int)blockIdx.x) : (int)blockIdx.x;
        __syncthreads();   // protect HT reads of previous half before re-zero
        if (tid < TP) {
            int pg = perm[tile * TP + tid];
            pgs[tid] = pg;
            lns[tid] = lens[pg];
        }
        for (int i = tid; i < DIM * TP; i += 256) {
            ((float*)HT)[i] = 0.f;   // h0 = 0 (required)
            ((float*)XT)[i] = 0.f;   // avoid garbage in masked lanes
        }
        __syncthreads();
        int tmax = 0;
        for (int i = 0; i < TP; ++i) { int v = lns[i]; tmax = v > tmax ? v : tmax; }

        for (int t = 0; t < tmax; ++t) {
            // gather this step's link inputs (transposed into LDS)
            {
                const int pi = tid >> 4;            // 0..15
                const int k0 = (tid & 15) * 8;      // 0..120
                if (t < lns[pi]) {
                    const int e = edge_map[pgs[pi] * ML + t];
                    const float4* src = (const float4*)(inputs + e * DIM + k0);
                    float4 a = src[0], b = src[1];
                    XT[k0 + 0][pi] = a.x; XT[k0 + 1][pi] = a.y;
                    XT[k0 + 2][pi] = a.z; XT[k0 + 3][pi] = a.w;
                    XT[k0 + 4][pi] = b.x; XT[k0 + 5][pi] = b.y;
                    XT[k0 + 6][pi] = b.z; XT[k0 + 7][pi] = b.w;
                }
            }
            __syncthreads();

            // G = x@Wk (+b0) and h@Wr (+b1); z,r parts accumulated together,
            // h-candidate parts kept separate (cand = tanh(xh + r*hh))
            float az0[4], az1[4], ar0[4], ar1[4], ax0[4], ax1[4], ah0[4], ah1[4];
            #pragma unroll
            for (int i = 0; i < 4; ++i) {
                az0[i] = az1[i] = ar0[i] = ar1[i] = 0.f;
                ax0[i] = ax1[i] = ah0[i] = ah1[i] = 0.f;
            }
            const float* gkr = gk + d0;
            const float* grr = gr + d0;
            for (int k = 0; k < DIM; ++k) {
                const float2 wz  = *(const float2*)(gkr + k * 384);
                const float2 wr2 = *(const float2*)(gkr + k * 384 + 128);
                const float2 wh  = *(const float2*)(gkr + k * 384 + 256);
                const float2 uz  = *(const float2*)(grr + k * 384);
                const float2 ur2 = *(const float2*)(grr + k * 384 + 128);
                const float2 uh  = *(const float2*)(grr + k * 384 + 256);
                const float4 xv = *(const float4*)&XT[k][p0];   // wave-uniform broadcast
                const float4 hv = *(const float4*)&HT[k][p0];
                const float xs[4]  = {xv.x, xv.y, xv.z, xv.w};
                const float hss[4] = {hv.x, hv.y, hv.z, hv.w};
                #pragma unroll
                for (int i = 0; i < 4; ++i) {
                    az0[i] = fmaf(xs[i], wz.x,  az0[i]); az0[i] = fmaf(hss[i], uz.x,  az0[i]);
                    az1[i] = fmaf(xs[i], wz.y,  az1[i]); az1[i] = fmaf(hss[i], uz.y,  az1[i]);
                    ar0[i] = fmaf(xs[i], wr2.x, ar0[i]); ar0[i] = fmaf(hss[i], ur2.x, ar0[i]);
                    ar1[i] = fmaf(xs[i], wr2.y, ar1[i]); ar1[i] = fmaf(hss[i], ur2.y, ar1[i]);
                    ax0[i] = fmaf(xs[i], wh.x,  ax0[i]);
                    ax1[i] = fmaf(xs[i], wh.y,  ax1[i]);
                    ah0[i] = fmaf(hss[i], uh.x, ah0[i]);
                    ah1[i] = fmaf(hss[i], uh.y, ah1[i]);
                }
            }
            __syncthreads();   // all GEMM reads of HT done before update writes

            #pragma unroll
            for (int i = 0; i < 4; ++i) {
                const int pi = p0 + i;
                if (t < lns[pi]) {
                    const float z0 = 1.f / (1.f + expf(-(az0[i] + bz0)));
                    const float z1 = 1.f / (1.f + expf(-(az1[i] + bz1)));
                    const float r0 = 1.f / (1.f + expf(-(ar0[i] + br0)));
                    const float r1 = 1.f / (1.f + expf(-(ar1[i] + br1)));
                    const float c0 = tanhf(ax0[i] + bx0 + r0 * (ah0[i] + bh0));
                    const float c1 = tanhf(ax1[i] + bx1 + r1 * (ah1[i] + bh1));
                    const float ho0 = HT[d0][pi], ho1 = HT[d0 + 1][pi];
                    const float hn0 = z0 * ho0 + (1.f - z0) * c0;
                    const float hn1 = z1 * ho1 + (1.f - z1) * c1;
                    HT[d0][pi] = hn0;
                    HT[d0 + 1][pi] = hn1;
                    float2 o; o.x = hn0; o.y = hn1;
                    *(float2*)(hs + (pgs[pi] * ML + t) * DIM + d0) = o;
                }
            }
            // next-iter top barrier orders these writes before the next GEMM
        }

        // final h = last_state (thread reads only its own columns — no barrier needed)
        #pragma unroll
        for (int i = 0; i < 4; ++i) {
            const int pi = p0 + i;
            float2 o; o.x = HT[d0][pi]; o.y = HT[d0 + 1][pi];
            *(float2*)(last + pgs[pi] * DIM + d0) = o;
        }
    }
}

// ---------------- q = last@Wq ; kq = Wk@q ----------------

__global__ __launch_bounds__(256, 2) void k_qkq(
    const float* __restrict__ last, const float* __restrict__ wq,
    const float* __restrict__ wk, float* __restrict__ kq)
{
    __shared__ float LT[DIM][64];
    __shared__ float QT[DIM][64];
    const int tid = threadIdx.x;
    const int pb = blockIdx.x * 64;
    {   // stage last (transposed)
        const int p  = tid >> 2;
        const int dd = (tid & 3) * 32;
        const float4* src = (const float4*)(last + (pb + p) * DIM + dd);
        #pragma unroll
        for (int q = 0; q < 8; ++q) {
            float4 v = src[q];
            LT[dd + q * 4 + 0][p] = v.x; LT[dd + q * 4 + 1][p] = v.y;
            LT[dd + q * 4 + 2][p] = v.z; LT[dd + q * 4 + 3][p] = v.w;
        }
    }
    __syncthreads();
    const int e0 = (tid & 63) * 2;
    const int p0 = (tid >> 6) * 16;
    float a0[16], a1[16];
    #pragma unroll
    for (int i = 0; i < 16; ++i) { a0[i] = a1[i] = 0.f; }
    for (int d = 0; d < DIM; ++d) {
        const float2 w = *(const float2*)(wq + d * DIM + e0);
        #pragma unroll
        for (int i = 0; i < 16; ++i) {
            const float lv = LT[d][p0 + i];
            a0[i] = fmaf(lv, w.x, a0[i]);
            a1[i] = fmaf(lv, w.y, a1[i]);
        }
    }
    #pragma unroll
    for (int i = 0; i < 16; ++i) { QT[e0][p0 + i] = a0[i]; QT[e0 + 1][p0 + i] = a1[i]; }
    __syncthreads();
    // kq[p][d] = sum_e wk[d][e] * q[p][e]
    float b0a[16], b1a[16];
    #pragma unroll
    for (int i = 0; i < 16; ++i) { b0a[i] = b1a[i] = 0.f; }
    for (int e = 0; e < DIM; ++e) {
        const float w0 = wk[e0 * DIM + e];
        const float w1 = wk[(e0 + 1) * DIM + e];
        #pragma unroll
        for (int i = 0; i < 16; ++i) {
            const float qv = QT[e][p0 + i];
            b0a[i] = fmaf(qv, w0, b0a[i]);
            b1a[i] = fmaf(qv, w1, b1a[i]);
        }
    }
    #pragma unroll
    for (int i = 0; i < 16; ++i) {
        float2 o; o.x = b0a[i]; o.y = b1a[i];
        *(float2*)(kq + (pb + p0 + i) * DIM + e0) = o;
    }
}

// ---------------- attention finalize ----------------
// context = (sum_l (h_l . kq) * h_l) @ Wv  — one wave per path, hs read once.

__global__ __launch_bounds__(256) void k_attn(
    const float* __restrict__ hs, const float* __restrict__ kq,
    const int* __restrict__ lens, const float* __restrict__ wv,
    float* __restrict__ out)
{
    __shared__ float ctx[4][DIM];
    const int tid  = threadIdx.x;
    const int wave = tid >> 6;
    const int lane = tid & 63;
    const int p    = blockIdx.x * 4 + wave;
    const int ln   = lens[p];
    const float2 kqv = *(const float2*)(kq + p * DIM + lane * 2);
    float c0 = 0.f, c1 = 0.f;
    for (int l = 0; l < ln; ++l) {
        const float2 h = *(const float2*)(hs + (p * ML + l) * DIM + lane * 2);
        float s = h.x * kqv.x + h.y * kqv.y;
        #pragma unroll
        for (int off = 32; off > 0; off >>= 1) s += __shfl_xor(s, off, 64);
        c0 = fmaf(s, h.x, c0);
        c1 = fmaf(s, h.y, c1);
    }
    ctx[wave][lane * 2]     = c0;
    ctx[wave][lane * 2 + 1] = c1;
    __syncthreads();
    const int ee = lane * 2;
    float o0 = 0.f, o1 = 0.f;
    for (int d = 0; d < DIM; ++d) {
        const float cv = ctx[wave][d];
        const float2 w = *(const float2*)(wv + d * DIM + ee);
        o0 = fmaf(cv, w.x, o0);
        o1 = fmaf(cv, w.y, o1);
    }
    float2 o; o.x = o0; o.y = o1;
    *(float2*)(out + p * DIM + ee) = o;
}

// ---------------- launch ----------------

extern "C" void kernel_launch(void* const* d_in, const int* in_sizes, int n_in,
                              void* d_out, int out_size, void* d_ws, size_t ws_size,
                              hipStream_t stream)
{
    const float* inputs = (const float*)d_in[0];
    const int*   paths  = (const int*)d_in[1];
    const int*   idx    = (const int*)d_in[2];
    const int*   seqs   = (const int*)d_in[3];
    const int*   lens   = (const int*)d_in[4];
    const float* gk     = (const float*)d_in[5];
    const float* gr     = (const float*)d_in[6];
    const float* gb     = (const float*)d_in[7];
    const float* wq     = (const float*)d_in[8];
    const float* wk     = (const float*)d_in[9];
    const float* wv     = (const float*)d_in[10];
    float* out = (float*)d_out;
    const int total = in_sizes[1];

    // workspace layout (~186 MB)
    float* hs   = (float*)d_ws;                    // [NP][ML][DIM] f32
    float* last = hs + (size_t)NP * ML * DIM;      // [NP][DIM]
    float* kq   = last + (size_t)NP * DIM;         // [NP][DIM]
    int* edge_map = (int*)(kq + (size_t)NP * DIM); // [NP][ML]
    int* perm   = edge_map + NP * ML;              // [NP]
    int* counts = perm + NP;                       // [32]
    int* starts = counts + 32;                     // [32]

    k_zero_counts<<<1, 64, 0, stream>>>(counts);
    k_hist<<<NP / 256, 256, 0, stream>>>(lens, counts);
    k_prefix<<<1, 64, 0, stream>>>(counts, starts);
    k_perm<<<NP / 256, 256, 0, stream>>>(lens, starts, perm);
    k_edge<<<(total + 255) / 256, 256, 0, stream>>>(idx, seqs, paths, total, edge_map);
    k_gru<<<NT / 2, 256, 0, stream>>>(inputs, lens, gk, gr, gb, edge_map, perm, hs, last);
    k_qkq<<<NP / 64, 256, 0, stream>>>(last, wq, wk, kq);
    k_attn<<<NP / 4, 256, 0, stream>>>(hs, kq, lens, wv, out);
}

// Round 3
// 1151.778 us; speedup vs baseline: 1.1992x; 1.1992x over previous
//
#include <hip/hip_runtime.h>
#include <cstdint>

#define NP 16384     // paths
#define NE 4096      // edges
#define DIM 128      // link/path dim
#define ML 20        // max len
#define TP 16        // paths per GRU tile
#define NT (NP/TP)   // 1024 tiles

// ---------------- sort / setup kernels ----------------

__global__ void k_zero_counts(int* counts) {
    if (threadIdx.x < 32) counts[threadIdx.x] = 0;
}

__global__ void k_hist(const int* __restrict__ lens, int* counts) {
    int p = blockIdx.x * 256 + threadIdx.x;
    if (p < NP) atomicAdd(&counts[lens[p]], 1);
}

// descending-length order: longest bins get lowest start offsets so the
// longest tiles are dispatched first (better makespan with dynamic dispatch)
__global__ void k_prefix(const int* __restrict__ counts, int* starts) {
    if (threadIdx.x == 0) {
        int s = 0;
        for (int i = ML; i >= 0; --i) { starts[i] = s; s += counts[i]; }
    }
}

__global__ void k_perm(const int* __restrict__ lens, int* starts, int* perm) {
    int p = blockIdx.x * 256 + threadIdx.x;
    if (p < NP) {
        int pos = atomicAdd(&starts[lens[p]], 1);
        perm[pos] = p;  // order within a bin is nondeterministic; output is invariant
    }
}

__global__ void k_edge(const int* __restrict__ idx, const int* __restrict__ seqs,
                       const int* __restrict__ paths, int total, int* __restrict__ edge_map) {
    int i = blockIdx.x * 256 + threadIdx.x;
    if (i < total) edge_map[idx[i] * ML + seqs[i]] = paths[i];
}

// ---------------- fast activations ----------------
__device__ __forceinline__ float frcp(float x)  { return __builtin_amdgcn_rcpf(x); }
__device__ __forceinline__ float fsig(float x)  { return frcp(1.f + __expf(-x)); }
__device__ __forceinline__ float ftanh(float x) { float e = __expf(2.f * x); return 1.f - 2.f * frcp(e + 1.f); }

// ---------------- GRU forward ----------------
// 128 threads = 2 waves. Wave w owns paths p0=8w..8w+7; lane owns d-pair d0=2*lane.
// Per thread: 64 f32 accumulators (2 cols x 8 paths x {z,r,xh,hh}).
// X,H row-major in LDS -> GEMM reads are wave-uniform broadcasts (no bank conflicts).
// Weights streamed from L2 as float2 per lane (coalesced, L2-resident).

__global__ __launch_bounds__(128, 2) void k_gru(
    const float* __restrict__ inputs, const int* __restrict__ lens,
    const float* __restrict__ gk, const float* __restrict__ gr,
    const float* __restrict__ gb, const int* __restrict__ edge_map,
    const int* __restrict__ perm, float* __restrict__ hs, float* __restrict__ last)
{
    __shared__ float X[TP][DIM];   // 8 KB, row-major
    __shared__ float H[TP][DIM];   // 8 KB, row-major
    __shared__ int pgs[TP];
    __shared__ int lns[TP];

    const int tid  = threadIdx.x;
    const int lane = tid & 63;
    const int d0   = lane * 2;         // this thread's d-pair
    const int p0   = (tid >> 6) * 8;   // 8 paths per thread (wave-split)

    // biases (b0 = gb[0..383], b1 = gb[384..767]); z,r parts pre-summed
    const float bz0 = gb[d0]       + gb[384 + d0];
    const float bz1 = gb[d0 + 1]   + gb[384 + d0 + 1];
    const float br0 = gb[128 + d0] + gb[512 + d0];
    const float br1 = gb[128 + d0 + 1] + gb[512 + d0 + 1];
    const float bx0 = gb[256 + d0],     bx1 = gb[256 + d0 + 1];
    const float bh0 = gb[640 + d0],     bh1 = gb[640 + d0 + 1];

    const int tile = blockIdx.x;
    if (tid < TP) {
        int pg = perm[tile * TP + tid];
        pgs[tid] = pg;
        lns[tid] = lens[pg];
    }
    for (int i = tid; i < TP * DIM; i += 128) ((float*)H)[i] = 0.f;  // h0 = 0
    __syncthreads();
    int tmax = 0;
    #pragma unroll
    for (int i = 0; i < TP; ++i) { int v = lns[i]; tmax = v > tmax ? v : tmax; }

    const float* gkp = gk + d0;
    const float* grp = gr + d0;

    for (int t = 0; t < tmax; ++t) {
        // gather this step's link inputs (row-major copy, coalesced)
        {
            const int pi = tid >> 3;           // 0..15
            const int k0 = (tid & 7) * 16;     // 0..112
            if (t < lns[pi]) {
                const int e = edge_map[pgs[pi] * ML + t];
                const float4* s4 = (const float4*)(inputs + e * DIM + k0);
                float4 a = s4[0], b = s4[1], c = s4[2], d = s4[3];
                float4* dst = (float4*)&X[pi][k0];
                dst[0] = a; dst[1] = b; dst[2] = c; dst[3] = d;
            }
        }
        __syncthreads();

        // accumulate x@Wk and h@Wr; z,r halves summed together, cand parts separate
        float az0[8], az1[8], ar0[8], ar1[8], ax0[8], ax1[8], ah0[8], ah1[8];
        #pragma unroll
        for (int i = 0; i < 8; ++i) {
            az0[i] = az1[i] = ar0[i] = ar1[i] = 0.f;
            ax0[i] = ax1[i] = ah0[i] = ah1[i] = 0.f;
        }
        for (int kb = 0; kb < DIM; kb += 2) {
            float2 xv[8], hv[8];
            #pragma unroll
            for (int i = 0; i < 8; ++i) {
                xv[i] = *(const float2*)&X[p0 + i][kb];   // wave-uniform broadcast
                hv[i] = *(const float2*)&H[p0 + i][kb];
            }
            #pragma unroll
            for (int kk = 0; kk < 2; ++kk) {
                const int k = kb + kk;
                const float2 wz  = *(const float2*)(gkp + k * 384);
                const float2 wr2 = *(const float2*)(gkp + k * 384 + 128);
                const float2 wh  = *(const float2*)(gkp + k * 384 + 256);
                const float2 uz  = *(const float2*)(grp + k * 384);
                const float2 ur2 = *(const float2*)(grp + k * 384 + 128);
                const float2 uh  = *(const float2*)(grp + k * 384 + 256);
                #pragma unroll
                for (int i = 0; i < 8; ++i) {
                    const float xs = kk ? xv[i].y : xv[i].x;
                    const float hh = kk ? hv[i].y : hv[i].x;
                    az0[i] = fmaf(xs, wz.x,  az0[i]); az0[i] = fmaf(hh, uz.x,  az0[i]);
                    az1[i] = fmaf(xs, wz.y,  az1[i]); az1[i] = fmaf(hh, uz.y,  az1[i]);
                    ar0[i] = fmaf(xs, wr2.x, ar0[i]); ar0[i] = fmaf(hh, ur2.x, ar0[i]);
                    ar1[i] = fmaf(xs, wr2.y, ar1[i]); ar1[i] = fmaf(hh, ur2.y, ar1[i]);
                    ax0[i] = fmaf(xs, wh.x,  ax0[i]);
                    ax1[i] = fmaf(xs, wh.y,  ax1[i]);
                    ah0[i] = fmaf(hh, uh.x,  ah0[i]);
                    ah1[i] = fmaf(hh, uh.y,  ah1[i]);
                }
            }
        }
        __syncthreads();   // all GEMM reads of H done before update writes

        #pragma unroll
        for (int i = 0; i < 8; ++i) {
            const int pi = p0 + i;
            if (t < lns[pi]) {             // wave-uniform branch
                const float z0 = fsig(az0[i] + bz0);
                const float z1 = fsig(az1[i] + bz1);
                const float r0 = fsig(ar0[i] + br0);
                const float r1 = fsig(ar1[i] + br1);
                const float c0 = ftanh(ax0[i] + bx0 + r0 * (ah0[i] + bh0));
                const float c1 = ftanh(ax1[i] + bx1 + r1 * (ah1[i] + bh1));
                const float2 ho = *(const float2*)&H[pi][d0];
                float2 hn;
                hn.x = z0 * ho.x + (1.f - z0) * c0;
                hn.y = z1 * ho.y + (1.f - z1) * c1;
                *(float2*)&H[pi][d0] = hn;
                *(float2*)(hs + (pgs[pi] * ML + t) * DIM + d0) = hn;
            }
        }
        // next-iter top barrier orders these writes before the next GEMM
    }

    // final h = last_state (thread reads only its own elements — no barrier needed)
    #pragma unroll
    for (int i = 0; i < 8; ++i) {
        const int pi = p0 + i;
        float2 o = *(const float2*)&H[pi][d0];
        *(float2*)(last + pgs[pi] * DIM + d0) = o;
    }
}

// ---------------- q = last@Wq ; kq = Wk@q ----------------

__global__ __launch_bounds__(256, 2) void k_qkq(
    const float* __restrict__ last, const float* __restrict__ wq,
    const float* __restrict__ wk, float* __restrict__ kq)
{
    __shared__ float LT[DIM][64];
    __shared__ float QT[DIM][64];
    const int tid = threadIdx.x;
    const int pb = blockIdx.x * 64;
    {   // stage last (transposed)
        const int p  = tid >> 2;
        const int dd = (tid & 3) * 32;
        const float4* src = (const float4*)(last + (pb + p) * DIM + dd);
        #pragma unroll
        for (int q = 0; q < 8; ++q) {
            float4 v = src[q];
            LT[dd + q * 4 + 0][p] = v.x; LT[dd + q * 4 + 1][p] = v.y;
            LT[dd + q * 4 + 2][p] = v.z; LT[dd + q * 4 + 3][p] = v.w;
        }
    }
    __syncthreads();
    const int e0 = (tid & 63) * 2;
    const int p0 = (tid >> 6) * 16;
    float a0[16], a1[16];
    #pragma unroll
    for (int i = 0; i < 16; ++i) { a0[i] = a1[i] = 0.f; }
    for (int d = 0; d < DIM; ++d) {
        const float2 w = *(const float2*)(wq + d * DIM + e0);
        #pragma unroll
        for (int i = 0; i < 16; ++i) {
            const float lv = LT[d][p0 + i];
            a0[i] = fmaf(lv, w.x, a0[i]);
            a1[i] = fmaf(lv, w.y, a1[i]);
        }
    }
    #pragma unroll
    for (int i = 0; i < 16; ++i) { QT[e0][p0 + i] = a0[i]; QT[e0 + 1][p0 + i] = a1[i]; }
    __syncthreads();
    // kq[p][d] = sum_e wk[d][e] * q[p][e]
    float b0a[16], b1a[16];
    #pragma unroll
    for (int i = 0; i < 16; ++i) { b0a[i] = b1a[i] = 0.f; }
    for (int e = 0; e < DIM; ++e) {
        const float w0 = wk[e0 * DIM + e];
        const float w1 = wk[(e0 + 1) * DIM + e];
        #pragma unroll
        for (int i = 0; i < 16; ++i) {
            const float qv = QT[e][p0 + i];
            b0a[i] = fmaf(qv, w0, b0a[i]);
            b1a[i] = fmaf(qv, w1, b1a[i]);
        }
    }
    #pragma unroll
    for (int i = 0; i < 16; ++i) {
        float2 o; o.x = b0a[i]; o.y = b1a[i];
        *(float2*)(kq + (pb + p0 + i) * DIM + e0) = o;
    }
}

// ---------------- attention finalize ----------------
// context = (sum_l (h_l . kq) * h_l) @ Wv  — one wave per path, hs read once.

__global__ __launch_bounds__(256) void k_attn(
    const float* __restrict__ hs, const float* __restrict__ kq,
    const int* __restrict__ lens, const float* __restrict__ wv,
    float* __restrict__ out)
{
    __shared__ float ctx[4][DIM];
    const int tid  = threadIdx.x;
    const int wave = tid >> 6;
    const int lane = tid & 63;
    const int p    = blockIdx.x * 4 + wave;
    const int ln   = lens[p];
    const float2 kqv = *(const float2*)(kq + p * DIM + lane * 2);
    float c0 = 0.f, c1 = 0.f;
    for (int l = 0; l < ln; ++l) {
        const float2 h = *(const float2*)(hs + (p * ML + l) * DIM + lane * 2);
        float s = h.x * kqv.x + h.y * kqv.y;
        #pragma unroll
        for (int off = 32; off > 0; off >>= 1) s += __shfl_xor(s, off, 64);
        c0 = fmaf(s, h.x, c0);
        c1 = fmaf(s, h.y, c1);
    }
    ctx[wave][lane * 2]     = c0;
    ctx[wave][lane * 2 + 1] = c1;
    __syncthreads();
    const int ee = lane * 2;
    float o0 = 0.f, o1 = 0.f;
    for (int d = 0; d < DIM; ++d) {
        const float cv = ctx[wave][d];
        const float2 w = *(const float2*)(wv + d * DIM + ee);
        o0 = fmaf(cv, w.x, o0);
        o1 = fmaf(cv, w.y, o1);
    }
    float2 o; o.x = o0; o.y = o1;
    *(float2*)(out + p * DIM + ee) = o;
}

// ---------------- launch ----------------

extern "C" void kernel_launch(void* const* d_in, const int* in_sizes, int n_in,
                              void* d_out, int out_size, void* d_ws, size_t ws_size,
                              hipStream_t stream)
{
    const float* inputs = (const float*)d_in[0];
    const int*   paths  = (const int*)d_in[1];
    const int*   idx    = (const int*)d_in[2];
    const int*   seqs   = (const int*)d_in[3];
    const int*   lens   = (const int*)d_in[4];
    const float* gk     = (const float*)d_in[5];
    const float* gr     = (const float*)d_in[6];
    const float* gb     = (const float*)d_in[7];
    const float* wq     = (const float*)d_in[8];
    const float* wk     = (const float*)d_in[9];
    const float* wv     = (const float*)d_in[10];
    float* out = (float*)d_out;
    const int total = in_sizes[1];

    // workspace layout (~186 MB)
    float* hs   = (float*)d_ws;                    // [NP][ML][DIM] f32
    float* last = hs + (size_t)NP * ML * DIM;      // [NP][DIM]
    float* kq   = last + (size_t)NP * DIM;         // [NP][DIM]
    int* edge_map = (int*)(kq + (size_t)NP * DIM); // [NP][ML]
    int* perm   = edge_map + NP * ML;              // [NP]
    int* counts = perm + NP;                       // [32]
    int* starts = counts + 32;                     // [32]

    k_zero_counts<<<1, 64, 0, stream>>>(counts);
    k_hist<<<NP / 256, 256, 0, stream>>>(lens, counts);
    k_prefix<<<1, 64, 0, stream>>>(counts, starts);
    k_perm<<<NP / 256, 256, 0, stream>>>(lens, starts, perm);
    k_edge<<<(total + 255) / 256, 256, 0, stream>>>(idx, seqs, paths, total, edge_map);
    k_gru<<<NT, 128, 0, stream>>>(inputs, lens, gk, gr, gb, edge_map, perm, hs, last);
    k_qkq<<<NP / 64, 256, 0, stream>>>(last, wq, wk, kq);
    k_attn<<<NP / 4, 256, 0, stream>>>(hs, kq, lens, wv, out);
}

// Round 4
// 391.544 us; speedup vs baseline: 3.5276x; 2.9416x over previous
//
#include <hip/hip_runtime.h>
#include <cstdint>

#define NP 16384     // paths
#define NE 4096      // edges
#define DIM 128      // link/path dim
#define ML 20        // max len
#define TP 16        // paths per GRU tile
#define NT (NP/TP)   // 1024 tiles

typedef _Float16 f16;
typedef _Float16 f16x8 __attribute__((ext_vector_type(8)));
typedef _Float16 f16x2 __attribute__((ext_vector_type(2)));
typedef float    f32x4 __attribute__((ext_vector_type(4)));

// ---------------- sort / setup kernels ----------------

__global__ void k_zero_counts(int* counts) {
    if (threadIdx.x < 32) counts[threadIdx.x] = 0;
}

__global__ void k_hist(const int* __restrict__ lens, int* counts) {
    int p = blockIdx.x * 256 + threadIdx.x;
    if (p < NP) atomicAdd(&counts[lens[p]], 1);
}

// descending-length order: longest tiles dispatch first (balanced makespan)
__global__ void k_prefix(const int* __restrict__ counts, int* starts) {
    if (threadIdx.x == 0) {
        int s = 0;
        for (int i = ML; i >= 0; --i) { starts[i] = s; s += counts[i]; }
    }
}

__global__ void k_perm(const int* __restrict__ lens, int* starts, int* perm) {
    int p = blockIdx.x * 256 + threadIdx.x;
    if (p < NP) {
        int pos = atomicAdd(&starts[lens[p]], 1);
        perm[pos] = p;  // order within a bin nondeterministic; output invariant
    }
}

__global__ void k_edge(const int* __restrict__ idx, const int* __restrict__ seqs,
                       const int* __restrict__ paths, int total, int* __restrict__ edge_map) {
    int i = blockIdx.x * 256 + threadIdx.x;
    if (i < total) edge_map[idx[i] * ML + seqs[i]] = paths[i];
}

// ---------------- f16 conversion kernels ----------------
// Weights pre-transposed to B-fragment-friendly [col][k] layout.
// btz[n][kk] kk<128 -> gk[kk][n] ; kk>=128 -> gr[kk-128][n]   (merged K=256 z)
// btr same for r cols (n+128). btcx[n][k] = gk[k][256+n]; btch[n][k] = gr[k][256+n].
__global__ void k_cvt_w(const float* __restrict__ gk, const float* __restrict__ gr,
                        f16* __restrict__ btz, f16* __restrict__ btr,
                        f16* __restrict__ btcx, f16* __restrict__ btch) {
    int i = blockIdx.x * 256 + threadIdx.x;   // 16384 = 128 x 128
    int n = i >> 7, k = i & 127;
    btz[n*256 + k]        = (f16)gk[k*384 + n];
    btz[n*256 + 128 + k]  = (f16)gr[k*384 + n];
    btr[n*256 + k]        = (f16)gk[k*384 + 128 + n];
    btr[n*256 + 128 + k]  = (f16)gr[k*384 + 128 + n];
    btcx[n*128 + k]       = (f16)gk[k*384 + 256 + n];
    btch[n*128 + k]       = (f16)gr[k*384 + 256 + n];
}

__global__ void k_cvt_x(const float* __restrict__ inputs, f16* __restrict__ inx) {
    int i = blockIdx.x * 256 + threadIdx.x;   // NE*DIM = 524288
    inx[i] = (f16)inputs[i];
}

// ---------------- fast activations ----------------
__device__ __forceinline__ float frcp(float x)  { return __builtin_amdgcn_rcpf(x); }
__device__ __forceinline__ float fsig(float x)  { return frcp(1.f + __expf(-x)); }
__device__ __forceinline__ float ftanh(float x) { float e = __expf(2.f * x); return 1.f - 2.f * frcp(e + 1.f); }

// ---------------- GRU forward (MFMA f16) ----------------
// 512 thr = 8 waves; one 16-path tile per wg. Wave w owns col-slice [16w,16w+16)
// of each of z / r / cand. Per step per wave: 24 x mfma_f32_16x16x32_f16:
//   Az(K=256: x then h), Ar(K=256), Ax(K=128 x), Ah(K=128 h).
// B-fragments live in VGPRs for the whole t-loop (loaded once from L2).
// D-frag mapping (col=lane&15 -> n, row=(lane>>4)*4+reg -> path) is identical for
// all 4 accumulators -> GRU update is fully in-register; h_old in 4 VGPRs/lane.
// Only h crosses waves: 4KB XOR-swizzled f16 LDS buffer in A-frag chunk layout.

__global__ __launch_bounds__(512, 2) void k_gru(
    const f16* __restrict__ inx, const int* __restrict__ lens,
    const f16* __restrict__ btz, const f16* __restrict__ btr,
    const f16* __restrict__ btcx, const f16* __restrict__ btch,
    const float* __restrict__ gb, const int* __restrict__ edge_map,
    const int* __restrict__ perm, f16* __restrict__ hs, float* __restrict__ last)
{
    __shared__ f16 H16[TP * DIM];   // 4 KB, XOR-swizzled fragment layout
    __shared__ int pgs[TP], lns[TP];

    const int tid  = threadIdx.x;
    const int lane = tid & 63;
    const int w    = tid >> 6;       // wave 0..7
    const int nw   = w * 16;         // column-slice base
    const int arow = lane & 15;      // A-row (path for A-frags), D-col (n offset)
    const int agrp = lane >> 4;      // 0..3
    const int d    = nw + arow;      // this lane's output column (0..127)

    if (tid < TP) { int pg = perm[blockIdx.x * TP + tid]; pgs[tid] = pg; lns[tid] = lens[pg]; }
    for (int i = tid; i < TP * DIM; i += 512) H16[i] = (f16)0.f;   // h0 = 0
    __syncthreads();

    int tmax = 0;
    #pragma unroll
    for (int i = 0; i < TP; ++i) tmax = max(tmax, lns[i]);

    // B fragments (time-invariant) -> registers. 24 frags x 4 VGPR = 96 VGPRs.
    f16x8 Bz[8], Br[8], Bx[4], Bh[4];
    {
        const int cb = d * 256 + agrp * 8;
        #pragma unroll
        for (int ks = 0; ks < 8; ++ks) {
            Bz[ks] = *(const f16x8*)(btz + cb + ks * 32);
            Br[ks] = *(const f16x8*)(btr + cb + ks * 32);
        }
        const int cc = d * 128 + agrp * 8;
        #pragma unroll
        for (int ks = 0; ks < 4; ++ks) {
            Bx[ks] = *(const f16x8*)(btcx + cc + ks * 32);
            Bh[ks] = *(const f16x8*)(btch + cc + ks * 32);
        }
    }

    // biases for column d (z,r halves pre-summed)
    const float bzc = gb[d]       + gb[384 + d];
    const float brc = gb[128 + d] + gb[512 + d];
    const float bxc = gb[256 + d];
    const float bhc = gb[640 + d];

    // per-lane state: 4 paths (agrp*4+r) at column d
    float hold[4] = {0.f, 0.f, 0.f, 0.f};
    int ln4[4], hsrow[4], h16a[4], pg4[4];
    #pragma unroll
    for (int r = 0; r < 4; ++r) {
        const int p = agrp * 4 + r;
        ln4[r]   = lns[p];
        pg4[r]   = pgs[p];
        hsrow[r] = pgs[p] * ML;
        h16a[r]  = p * DIM + (((d >> 3) ^ (p & 7)) * 8) + (d & 7);
    }

    const int ep = pgs[arow] * ML;   // x-gather base (A-frag path = arow)

    // x fragments for t=0
    f16x8 xa[4];
    {
        const int e = edge_map[ep] & (NE - 1);
        const f16* xp = inx + e * DIM + agrp * 8;
        #pragma unroll
        for (int ks = 0; ks < 4; ++ks) xa[ks] = *(const f16x8*)(xp + ks * 32);
    }

    for (int t = 0; t < tmax; ++t) {
        // h fragments from LDS (chunk-XOR swizzle: conflict-free b128 reads)
        f16x8 ha[4];
        #pragma unroll
        for (int ks = 0; ks < 4; ++ks) {
            const int chunk = (ks * 4 + agrp) ^ (arow & 7);
            ha[ks] = *(const f16x8*)(H16 + arow * DIM + chunk * 8);
        }

        f32x4 Az = {0.f,0.f,0.f,0.f}, Ar = {0.f,0.f,0.f,0.f};
        f32x4 Ax = {0.f,0.f,0.f,0.f}, Ah = {0.f,0.f,0.f,0.f};
        #pragma unroll
        for (int ks = 0; ks < 4; ++ks) {
            Az = __builtin_amdgcn_mfma_f32_16x16x32_f16(xa[ks], Bz[ks], Az, 0, 0, 0);
            Ar = __builtin_amdgcn_mfma_f32_16x16x32_f16(xa[ks], Br[ks], Ar, 0, 0, 0);
            Ax = __builtin_amdgcn_mfma_f32_16x16x32_f16(xa[ks], Bx[ks], Ax, 0, 0, 0);
        }
        #pragma unroll
        for (int ks = 0; ks < 4; ++ks) {
            Az = __builtin_amdgcn_mfma_f32_16x16x32_f16(ha[ks], Bz[4 + ks], Az, 0, 0, 0);
            Ar = __builtin_amdgcn_mfma_f32_16x16x32_f16(ha[ks], Br[4 + ks], Ar, 0, 0, 0);
            Ah = __builtin_amdgcn_mfma_f32_16x16x32_f16(ha[ks], Bh[ks],     Ah, 0, 0, 0);
        }

        // prefetch next step's x fragments (hides L2 latency under update)
        {
            const int tn = (t + 1 < ML) ? (t + 1) : (ML - 1);
            const int e = edge_map[ep + tn] & (NE - 1);   // mask: poison-safe
            const f16* xp = inx + e * DIM + agrp * 8;
            #pragma unroll
            for (int ks = 0; ks < 4; ++ks) xa[ks] = *(const f16x8*)(xp + ks * 32);
        }
        __syncthreads();   // all waves done reading old H16

        // in-register GRU update: lane owns (path=agrp*4+r, col=d)
        #pragma unroll
        for (int r = 0; r < 4; ++r) {
            const float z  = fsig(Az[r] + bzc);
            const float rg = fsig(Ar[r] + brc);
            const float c  = ftanh(Ax[r] + bxc + rg * (Ah[r] + bhc));
            const float hn = z * hold[r] + (1.f - z) * c;
            if (t < ln4[r]) {                 // mask: freeze h past length
                hold[r] = hn;
                const f16 hv = (f16)hn;
                H16[h16a[r]] = hv;
                hs[(hsrow[r] + t) * DIM + d] = hv;
            }
        }
        __syncthreads();   // new H16 visible for next step
    }

    // last_state
    #pragma unroll
    for (int r = 0; r < 4; ++r)
        last[pg4[r] * DIM + d] = hold[r];
}

// ---------------- q = last@Wq ; kq = Wk@q ----------------

__global__ __launch_bounds__(256, 2) void k_qkq(
    const float* __restrict__ last, const float* __restrict__ wq,
    const float* __restrict__ wk, float* __restrict__ kq)
{
    __shared__ float LT[DIM][64];
    __shared__ float QT[DIM][64];
    const int tid = threadIdx.x;
    const int pb = blockIdx.x * 64;
    {   // stage last (transposed)
        const int p  = tid >> 2;
        const int dd = (tid & 3) * 32;
        const float4* src = (const float4*)(last + (pb + p) * DIM + dd);
        #pragma unroll
        for (int q = 0; q < 8; ++q) {
            float4 v = src[q];
            LT[dd + q * 4 + 0][p] = v.x; LT[dd + q * 4 + 1][p] = v.y;
            LT[dd + q * 4 + 2][p] = v.z; LT[dd + q * 4 + 3][p] = v.w;
        }
    }
    __syncthreads();
    const int e0 = (tid & 63) * 2;
    const int p0 = (tid >> 6) * 16;
    float a0[16], a1[16];
    #pragma unroll
    for (int i = 0; i < 16; ++i) { a0[i] = a1[i] = 0.f; }
    for (int dd = 0; dd < DIM; ++dd) {
        const float2 ww = *(const float2*)(wq + dd * DIM + e0);
        #pragma unroll
        for (int i = 0; i < 16; ++i) {
            const float lv = LT[dd][p0 + i];
            a0[i] = fmaf(lv, ww.x, a0[i]);
            a1[i] = fmaf(lv, ww.y, a1[i]);
        }
    }
    #pragma unroll
    for (int i = 0; i < 16; ++i) { QT[e0][p0 + i] = a0[i]; QT[e0 + 1][p0 + i] = a1[i]; }
    __syncthreads();
    // kq[p][d] = sum_e wk[d][e] * q[p][e]
    float b0a[16], b1a[16];
    #pragma unroll
    for (int i = 0; i < 16; ++i) { b0a[i] = b1a[i] = 0.f; }
    for (int e = 0; e < DIM; ++e) {
        const float w0 = wk[e0 * DIM + e];
        const float w1 = wk[(e0 + 1) * DIM + e];
        #pragma unroll
        for (int i = 0; i < 16; ++i) {
            const float qv = QT[e][p0 + i];
            b0a[i] = fmaf(qv, w0, b0a[i]);
            b1a[i] = fmaf(qv, w1, b1a[i]);
        }
    }
    #pragma unroll
    for (int i = 0; i < 16; ++i) {
        float2 o; o.x = b0a[i]; o.y = b1a[i];
        *(float2*)(kq + (pb + p0 + i) * DIM + e0) = o;
    }
}

// ---------------- attention finalize ----------------
// context = (sum_l (h_l . kq) * h_l) @ Wv  — one wave per path; hs is f16 now.

__global__ __launch_bounds__(256) void k_attn(
    const f16* __restrict__ hs, const float* __restrict__ kq,
    const int* __restrict__ lens, const float* __restrict__ wv,
    float* __restrict__ out)
{
    __shared__ float ctx[4][DIM];
    const int tid  = threadIdx.x;
    const int wave = tid >> 6;
    const int lane = tid & 63;
    const int p    = blockIdx.x * 4 + wave;
    const int ln   = lens[p];
    const float2 kqv = *(const float2*)(kq + p * DIM + lane * 2);
    float c0 = 0.f, c1 = 0.f;
    for (int l = 0; l < ln; ++l) {
        const f16x2 h2 = *(const f16x2*)(hs + (p * ML + l) * DIM + lane * 2);
        const float hx = (float)h2.x, hy = (float)h2.y;
        float s = hx * kqv.x + hy * kqv.y;
        #pragma unroll
        for (int off = 32; off > 0; off >>= 1) s += __shfl_xor(s, off, 64);
        c0 = fmaf(s, hx, c0);
        c1 = fmaf(s, hy, c1);
    }
    ctx[wave][lane * 2]     = c0;
    ctx[wave][lane * 2 + 1] = c1;
    __syncthreads();
    const int ee = lane * 2;
    float o0 = 0.f, o1 = 0.f;
    for (int dd = 0; dd < DIM; ++dd) {
        const float cv = ctx[wave][dd];
        const float2 ww = *(const float2*)(wv + dd * DIM + ee);
        o0 = fmaf(cv, ww.x, o0);
        o1 = fmaf(cv, ww.y, o1);
    }
    float2 o; o.x = o0; o.y = o1;
    *(float2*)(out + p * DIM + ee) = o;
}

// ---------------- launch ----------------

extern "C" void kernel_launch(void* const* d_in, const int* in_sizes, int n_in,
                              void* d_out, int out_size, void* d_ws, size_t ws_size,
                              hipStream_t stream)
{
    const float* inputs = (const float*)d_in[0];
    const int*   paths  = (const int*)d_in[1];
    const int*   idx    = (const int*)d_in[2];
    const int*   seqs   = (const int*)d_in[3];
    const int*   lens   = (const int*)d_in[4];
    const float* gk     = (const float*)d_in[5];
    const float* gr     = (const float*)d_in[6];
    const float* gb     = (const float*)d_in[7];
    const float* wq     = (const float*)d_in[8];
    const float* wk     = (const float*)d_in[9];
    const float* wv     = (const float*)d_in[10];
    float* out = (float*)d_out;
    const int total = in_sizes[1];

    // workspace layout (~103 MB)
    float* last = (float*)d_ws;                        // [NP][DIM] f32
    float* kq   = last + (size_t)NP * DIM;             // [NP][DIM] f32
    f16*   hs   = (f16*)(kq + (size_t)NP * DIM);       // [NP][ML][DIM] f16
    f16*   inx  = hs + (size_t)NP * ML * DIM;          // [NE][DIM] f16
    f16*   btz  = inx + (size_t)NE * DIM;              // [128][256] f16
    f16*   btr  = btz + 128 * 256;                     // [128][256]
    f16*   btcx = btr + 128 * 256;                     // [128][128]
    f16*   btch = btcx + 128 * 128;                    // [128][128]
    int* edge_map = (int*)(btch + 128 * 128);          // [NP][ML]
    int* perm   = edge_map + NP * ML;                  // [NP]
    int* counts = perm + NP;                           // [32]
    int* starts = counts + 32;                         // [32]

    k_zero_counts<<<1, 64, 0, stream>>>(counts);
    k_hist<<<NP / 256, 256, 0, stream>>>(lens, counts);
    k_prefix<<<1, 64, 0, stream>>>(counts, starts);
    k_perm<<<NP / 256, 256, 0, stream>>>(lens, starts, perm);
    k_edge<<<(total + 255) / 256, 256, 0, stream>>>(idx, seqs, paths, total, edge_map);
    k_cvt_w<<<64, 256, 0, stream>>>(gk, gr, btz, btr, btcx, btch);
    k_cvt_x<<<(NE * DIM) / 256, 256, 0, stream>>>(inputs, inx);
    k_gru<<<NT, 512, 0, stream>>>(inx, lens, btz, btr, btcx, btch, gb, edge_map, perm, hs, last);
    k_qkq<<<NP / 64, 256, 0, stream>>>(last, wq, wk, kq);
    k_attn<<<NP / 4, 256, 0, stream>>>(hs, kq, lens, wv, out);
}

// Round 8
// 290.101 us; speedup vs baseline: 4.7612x; 1.3497x over previous
//
#include <hip/hip_runtime.h>
#include <cstdint>

#define NP 16384     // paths
#define NE 4096      // edges
#define DIM 128      // link/path dim
#define ML 20        // max len
#define TP 16        // paths per GRU tile
#define NT (NP/TP)   // 1024 tiles

typedef _Float16 f16;
typedef _Float16 f16x8 __attribute__((ext_vector_type(8)));
typedef _Float16 f16x2 __attribute__((ext_vector_type(2)));
typedef float    f32x4 __attribute__((ext_vector_type(4)));

// ---------------- setup: single-wg counting sort (descending length) ----------------
__global__ __launch_bounds__(1024) void k_sort(const int* __restrict__ lens,
                                               int* __restrict__ perm) {
    __shared__ int cnt[ML + 1];
    const int tid = threadIdx.x;
    if (tid <= ML) cnt[tid] = 0;
    __syncthreads();
    for (int p = tid; p < NP; p += 1024) atomicAdd(&cnt[lens[p]], 1);
    __syncthreads();
    if (tid == 0) {   // descending prefix: longest bins first
        int s = 0;
        for (int i = ML; i >= 0; --i) { int c = cnt[i]; cnt[i] = s; s += c; }
    }
    __syncthreads();
    for (int p = tid; p < NP; p += 1024) {
        int pos = atomicAdd(&cnt[lens[p]], 1);
        perm[pos] = p;   // order within a bin nondeterministic; output invariant
    }
}

// ---------------- setup: fused edge scatter + f16 converts ----------------
// Weights pre-transposed to B-fragment [col][k] layout:
// btz[n][k<128]=gk[k][n], btz[n][128+k]=gr[k][n] (merged K=256 for z); btr same
// for r cols (+128). btcx[n][k]=gk[k][256+n]; btch[n][k]=gr[k][256+n].
__global__ void k_prep(const int* __restrict__ idx, const int* __restrict__ seqs,
                       const int* __restrict__ paths, int total,
                       const float* __restrict__ inputs,
                       const float* __restrict__ gk, const float* __restrict__ gr,
                       int* __restrict__ edge_map, f16* __restrict__ inx,
                       f16* __restrict__ btz, f16* __restrict__ btr,
                       f16* __restrict__ btcx, f16* __restrict__ btch) {
    const int i = blockIdx.x * 256 + threadIdx.x;   // grid covers NE*DIM = 524288
    if (i < total) edge_map[idx[i] * ML + seqs[i]] = paths[i];
    inx[i] = (f16)inputs[i];
    if (i < 16384) {
        const int n = i >> 7, k = i & 127;
        btz[n*256 + k]       = (f16)gk[k*384 + n];
        btz[n*256 + 128 + k] = (f16)gr[k*384 + n];
        btr[n*256 + k]       = (f16)gk[k*384 + 128 + n];
        btr[n*256 + 128 + k] = (f16)gr[k*384 + 128 + n];
        btcx[n*128 + k]      = (f16)gk[k*384 + 256 + n];
        btch[n*128 + k]      = (f16)gr[k*384 + 256 + n];
    }
}

// ---------------- fast activations ----------------
__device__ __forceinline__ float frcp(float x)  { return __builtin_amdgcn_rcpf(x); }
__device__ __forceinline__ float fsig(float x)  { return frcp(1.f + __expf(-x)); }
__device__ __forceinline__ float ftanh(float x) { float e = __expf(2.f * x); return 1.f - 2.f * frcp(e + 1.f); }

// ---------------- GRU forward (MFMA f16) ----------------
// 512 thr = 8 waves; one 16-path tile per wg. Wave w owns col-slice [16w,16w+16).
// Per step per wave: 24 x mfma_f32_16x16x32_f16 (Az K=256, Ar K=256, Ax/Ah K=128).
// Ping-pong H16 + raw s_barrier with lgkmcnt-only wait -> ONE barrier per step and
// no vmcnt drain (hs stores and x prefetch float across barriers).
// Edge ids prefetched 2 steps ahead, x fragments 1 step ahead (breaks the
// dependent edge_map->inx L2 chain). GRU update fully in-register.

__global__ __launch_bounds__(512, 2) void k_gru(
    const f16* __restrict__ inx, const int* __restrict__ lens,
    const f16* __restrict__ btz, const f16* __restrict__ btr,
    const f16* __restrict__ btcx, const f16* __restrict__ btch,
    const float* __restrict__ gb, const int* __restrict__ edge_map,
    const int* __restrict__ perm, f16* __restrict__ hs, float* __restrict__ last)
{
    __shared__ f16 H16[2][TP * DIM];   // 2 x 4 KB ping-pong, XOR-swizzled frag layout
    __shared__ int pgs[TP], lns[TP];

    const int tid  = threadIdx.x;
    const int lane = tid & 63;
    const int w    = tid >> 6;       // wave 0..7
    const int nw   = w * 16;         // column-slice base
    const int arow = lane & 15;      // A-row (path), D-col (n offset)
    const int agrp = lane >> 4;      // 0..3
    const int d    = nw + arow;      // this lane's output column (0..127)

    if (tid < TP) { int pg = perm[blockIdx.x * TP + tid]; pgs[tid] = pg; lns[tid] = lens[pg]; }
    for (int i = tid; i < TP * DIM; i += 512) H16[0][i] = (f16)0.f;   // h0 = 0
    asm volatile("s_waitcnt lgkmcnt(0)" ::: "memory");
    __builtin_amdgcn_s_barrier();

    int tmax = 0;
    #pragma unroll
    for (int i = 0; i < TP; ++i) tmax = max(tmax, lns[i]);

    // B fragments (time-invariant) -> registers/AGPRs. 24 frags x 4 regs.
    f16x8 Bz[8], Br[8], Bx[4], Bh[4];
    {
        const int cb = d * 256 + agrp * 8;
        #pragma unroll
        for (int ks = 0; ks < 8; ++ks) {
            Bz[ks] = *(const f16x8*)(btz + cb + ks * 32);
            Br[ks] = *(const f16x8*)(btr + cb + ks * 32);
        }
        const int cc = d * 128 + agrp * 8;
        #pragma unroll
        for (int ks = 0; ks < 4; ++ks) {
            Bx[ks] = *(const f16x8*)(btcx + cc + ks * 32);
            Bh[ks] = *(const f16x8*)(btch + cc + ks * 32);
        }
    }

    // biases for column d (z,r halves pre-summed)
    const float bzc = gb[d]       + gb[384 + d];
    const float brc = gb[128 + d] + gb[512 + d];
    const float bxc = gb[256 + d];
    const float bhc = gb[640 + d];

    // per-lane state: 4 paths (agrp*4+r) at column d
    float hold[4] = {0.f, 0.f, 0.f, 0.f};
    int ln4[4], hsrow[4], h16a[4], pg4[4];
    #pragma unroll
    for (int r = 0; r < 4; ++r) {
        const int p = agrp * 4 + r;
        ln4[r]   = lns[p];
        pg4[r]   = pgs[p];
        hsrow[r] = pgs[p] * ML;
        h16a[r]  = p * DIM + (((d >> 3) ^ (p & 7)) * 8) + (d & 7);
    }

    const int ep = pgs[arow] * ML;   // x-gather base (A-frag path = arow)

    // 2-deep prefetch pipeline: e for t+1 already loaded, xa for t resident
    f16x8 xa[4];
    int e_nxt;
    {
        const int e0 = edge_map[ep] & (NE - 1);
        const f16* xp = inx + e0 * DIM + agrp * 8;
        #pragma unroll
        for (int ks = 0; ks < 4; ++ks) xa[ks] = *(const f16x8*)(xp + ks * 32);
        e_nxt = edge_map[ep + ((1 < ML) ? 1 : 0)];
    }

    for (int t = 0; t < tmax; ++t) {
        const f16* Hc = &H16[t & 1][0];
        f16*       Hn = &H16[(t & 1) ^ 1][0];

        // h fragments from LDS (chunk-XOR swizzle: conflict-free b128 reads)
        f16x8 ha[4];
        #pragma unroll
        for (int ks = 0; ks < 4; ++ks) {
            const int chunk = (ks * 4 + agrp) ^ (arow & 7);
            ha[ks] = *(const f16x8*)(Hc + arow * DIM + chunk * 8);
        }

        f32x4 Az = {0.f,0.f,0.f,0.f}, Ar = {0.f,0.f,0.f,0.f};
        f32x4 Ax = {0.f,0.f,0.f,0.f}, Ah = {0.f,0.f,0.f,0.f};
        #pragma unroll
        for (int ks = 0; ks < 4; ++ks) {
            Az = __builtin_amdgcn_mfma_f32_16x16x32_f16(xa[ks], Bz[ks], Az, 0, 0, 0);
            Ar = __builtin_amdgcn_mfma_f32_16x16x32_f16(xa[ks], Br[ks], Ar, 0, 0, 0);
            Ax = __builtin_amdgcn_mfma_f32_16x16x32_f16(xa[ks], Bx[ks], Ax, 0, 0, 0);
        }
        #pragma unroll
        for (int ks = 0; ks < 4; ++ks) {
            Az = __builtin_amdgcn_mfma_f32_16x16x32_f16(ha[ks], Bz[4 + ks], Az, 0, 0, 0);
            Ar = __builtin_amdgcn_mfma_f32_16x16x32_f16(ha[ks], Br[4 + ks], Ar, 0, 0, 0);
            Ah = __builtin_amdgcn_mfma_f32_16x16x32_f16(ha[ks], Bh[ks],     Ah, 0, 0, 0);
        }

        // x for t+1 from edge id loaded at t-1; edge id for t+2 issued now
        {
            const int e = e_nxt & (NE - 1);             // mask: poison-safe
            const f16* xp = inx + e * DIM + agrp * 8;
            #pragma unroll
            for (int ks = 0; ks < 4; ++ks) xa[ks] = *(const f16x8*)(xp + ks * 32);
            const int tn2 = (t + 2 < ML) ? (t + 2) : (ML - 1);
            e_nxt = edge_map[ep + tn2];
        }

        // in-register GRU update: lane owns (path=agrp*4+r, col=d); branchless
        #pragma unroll
        for (int r = 0; r < 4; ++r) {
            const float z  = fsig(Az[r] + bzc);
            const float rg = fsig(Ar[r] + brc);
            const float c  = ftanh(Ax[r] + bxc + rg * (Ah[r] + bhc));
            const float hn = z * hold[r] + (1.f - z) * c;
            hold[r] = (t < ln4[r]) ? hn : hold[r];      // freeze past length
            const f16 hv = (f16)hold[r];
            Hn[h16a[r]] = hv;                           // unconditional (frozen ok)
            hs[(hsrow[r] + t) * DIM + d] = hv;          // junk rows beyond len unread
        }

        // LDS-only hand-off: ds_writes visible, then barrier. Global ops float.
        asm volatile("s_waitcnt lgkmcnt(0)" ::: "memory");
        __builtin_amdgcn_s_barrier();
    }

    // last_state
    #pragma unroll
    for (int r = 0; r < 4; ++r)
        last[pg4[r] * DIM + d] = hold[r];
}

// ---------------- q = last@Wq ; kq = Wk@q ----------------

__global__ __launch_bounds__(256, 2) void k_qkq(
    const float* __restrict__ last, const float* __restrict__ wq,
    const float* __restrict__ wk, float* __restrict__ kq)
{
    __shared__ float LT[DIM][64];
    __shared__ float QT[DIM][64];
    const int tid = threadIdx.x;
    const int pb = blockIdx.x * 64;
    {   // stage last (transposed)
        const int p  = tid >> 2;
        const int dd = (tid & 3) * 32;
        const float4* src = (const float4*)(last + (pb + p) * DIM + dd);
        #pragma unroll
        for (int q = 0; q < 8; ++q) {
            float4 v = src[q];
            LT[dd + q * 4 + 0][p] = v.x; LT[dd + q * 4 + 1][p] = v.y;
            LT[dd + q * 4 + 2][p] = v.z; LT[dd + q * 4 + 3][p] = v.w;
        }
    }
    __syncthreads();
    const int e0 = (tid & 63) * 2;
    const int p0 = (tid >> 6) * 16;
    float a0[16], a1[16];
    #pragma unroll
    for (int i = 0; i < 16; ++i) { a0[i] = a1[i] = 0.f; }
    for (int dd = 0; dd < DIM; ++dd) {
        const float2 ww = *(const float2*)(wq + dd * DIM + e0);
        #pragma unroll
        for (int i = 0; i < 16; ++i) {
            const float lv = LT[dd][p0 + i];
            a0[i] = fmaf(lv, ww.x, a0[i]);
            a1[i] = fmaf(lv, ww.y, a1[i]);
        }
    }
    #pragma unroll
    for (int i = 0; i < 16; ++i) { QT[e0][p0 + i] = a0[i]; QT[e0 + 1][p0 + i] = a1[i]; }
    __syncthreads();
    // kq[p][d] = sum_e wk[d][e] * q[p][e]
    float b0a[16], b1a[16];
    #pragma unroll
    for (int i = 0; i < 16; ++i) { b0a[i] = b1a[i] = 0.f; }
    for (int e = 0; e < DIM; ++e) {
        const float w0 = wk[e0 * DIM + e];
        const float w1 = wk[(e0 + 1) * DIM + e];
        #pragma unroll
        for (int i = 0; i < 16; ++i) {
            const float qv = QT[e][p0 + i];
            b0a[i] = fmaf(qv, w0, b0a[i]);
            b1a[i] = fmaf(qv, w1, b1a[i]);
        }
    }
    #pragma unroll
    for (int i = 0; i < 16; ++i) {
        float2 o; o.x = b0a[i]; o.y = b1a[i];
        *(float2*)(kq + (pb + p0 + i) * DIM + e0) = o;
    }
}

// ---------------- attention finalize ----------------
// context = (sum_l (h_l . kq) * h_l) @ Wv  — one wave per path; hs is f16.

__global__ __launch_bounds__(256) void k_attn(
    const f16* __restrict__ hs, const float* __restrict__ kq,
    const int* __restrict__ lens, const float* __restrict__ wv,
    float* __restrict__ out)
{
    __shared__ float ctx[4][DIM];
    const int tid  = threadIdx.x;
    const int wave = tid >> 6;
    const int lane = tid & 63;
    const int p    = blockIdx.x * 4 + wave;
    const int ln   = lens[p];
    const float2 kqv = *(const float2*)(kq + p * DIM + lane * 2);
    float c0 = 0.f, c1 = 0.f;
    for (int l = 0; l < ln; ++l) {
        const f16x2 h2 = *(const f16x2*)(hs + (p * ML + l) * DIM + lane * 2);
        const float hx = (float)h2.x, hy = (float)h2.y;
        float s = hx * kqv.x + hy * kqv.y;
        #pragma unroll
        for (int off = 32; off > 0; off >>= 1) s += __shfl_xor(s, off, 64);
        c0 = fmaf(s, hx, c0);
        c1 = fmaf(s, hy, c1);
    }
    ctx[wave][lane * 2]     = c0;
    ctx[wave][lane * 2 + 1] = c1;
    __syncthreads();
    const int ee = lane * 2;
    float o0 = 0.f, o1 = 0.f;
    for (int dd = 0; dd < DIM; ++dd) {
        const float cv = ctx[wave][dd];
        const float2 ww = *(const float2*)(wv + dd * DIM + ee);
        o0 = fmaf(cv, ww.x, o0);
        o1 = fmaf(cv, ww.y, o1);
    }
    float2 o; o.x = o0; o.y = o1;
    *(float2*)(out + p * DIM + ee) = o;
}

// ---------------- launch ----------------

extern "C" void kernel_launch(void* const* d_in, const int* in_sizes, int n_in,
                              void* d_out, int out_size, void* d_ws, size_t ws_size,
                              hipStream_t stream)
{
    const float* inputs = (const float*)d_in[0];
    const int*   paths  = (const int*)d_in[1];
    const int*   idx    = (const int*)d_in[2];
    const int*   seqs   = (const int*)d_in[3];
    const int*   lens   = (const int*)d_in[4];
    const float* gk     = (const float*)d_in[5];
    const float* gr     = (const float*)d_in[6];
    const float* gb     = (const float*)d_in[7];
    const float* wq     = (const float*)d_in[8];
    const float* wk     = (const float*)d_in[9];
    const float* wv     = (const float*)d_in[10];
    float* out = (float*)d_out;
    const int total = in_sizes[1];

    // workspace layout (~103 MB)
    float* last = (float*)d_ws;                        // [NP][DIM] f32
    float* kq   = last + (size_t)NP * DIM;             // [NP][DIM] f32
    f16*   hs   = (f16*)(kq + (size_t)NP * DIM);       // [NP][ML][DIM] f16
    f16*   inx  = hs + (size_t)NP * ML * DIM;          // [NE][DIM] f16
    f16*   btz  = inx + (size_t)NE * DIM;              // [128][256] f16
    f16*   btr  = btz + 128 * 256;                     // [128][256]
    f16*   btcx = btr + 128 * 256;                     // [128][128]
    f16*   btch = btcx + 128 * 128;                    // [128][128]
    int* edge_map = (int*)(btch + 128 * 128);          // [NP][ML]
    int* perm   = edge_map + NP * ML;                  // [NP]

    k_sort<<<1, 1024, 0, stream>>>(lens, perm);
    k_prep<<<(NE * DIM) / 256, 256, 0, stream>>>(idx, seqs, paths, total, inputs,
                                                 gk, gr, edge_map, inx,
                                                 btz, btr, btcx, btch);
    k_gru<<<NT, 512, 0, stream>>>(inx, lens, btz, btr, btcx, btch, gb, edge_map, perm, hs, last);
    k_qkq<<<NP / 64, 256, 0, stream>>>(last, wq, wk, kq);
    k_attn<<<NP / 4, 256, 0, stream>>>(hs, kq, lens, wv, out);
}

// Round 9
// 282.390 us; speedup vs baseline: 4.8912x; 1.0273x over previous
//
#include <hip/hip_runtime.h>
#include <cstdint>

#define NP 16384     // paths
#define NE 4096      // edges
#define DIM 128      // link/path dim
#define ML 20        // max len
#define TP 32        // paths per GRU tile (2 row-tiles of 16)
#define NT (NP/TP)   // 512 tiles

typedef _Float16 f16;
typedef _Float16 f16x8 __attribute__((ext_vector_type(8)));
typedef _Float16 f16x2 __attribute__((ext_vector_type(2)));
typedef float    f32x4 __attribute__((ext_vector_type(4)));

// ---------------- setup: wave-parallel counting sort (descending length) ----------------
// Per-wave private histograms (stride 33 kills bank aliasing), per-bin parallel
// offset prefix, wave-private atomic placement. Same perm semantics as before
// (descending bins; order within bin nondeterministic; output invariant).
__global__ __launch_bounds__(1024) void k_sort(const int* __restrict__ lens,
                                               int* __restrict__ perm) {
    __shared__ int wcnt[16][33];
    __shared__ int start[ML + 1];
    const int tid = threadIdx.x;
    const int wv  = tid >> 6;
    for (int i = tid; i < 16 * 33; i += 1024) ((int*)wcnt)[i] = 0;
    __syncthreads();
    #pragma unroll
    for (int k = 0; k < NP / 1024; ++k) {
        const int p = k * 1024 + tid;
        atomicAdd(&wcnt[wv][lens[p]], 1);   // wave-private: low contention
    }
    __syncthreads();
    if (tid == 0) {   // descending bin starts: longest first
        int s = 0;
        for (int i = ML; i >= 0; --i) {
            int c = 0;
            #pragma unroll
            for (int w2 = 0; w2 < 16; ++w2) c += wcnt[w2][i];
            start[i] = s; s += c;
        }
    }
    __syncthreads();
    if (tid <= ML) {  // per-bin: convert wave counts -> wave offsets
        int running = start[tid];
        #pragma unroll
        for (int w2 = 0; w2 < 16; ++w2) {
            int tmp = wcnt[w2][tid];
            wcnt[w2][tid] = running;
            running += tmp;
        }
    }
    __syncthreads();
    #pragma unroll
    for (int k = 0; k < NP / 1024; ++k) {
        const int p = k * 1024 + tid;
        int pos = atomicAdd(&wcnt[wv][lens[p]], 1);
        perm[pos] = p;
    }
}

// ---------------- setup: fused edge scatter + f16 converts ----------------
// Weights pre-transposed to B-fragment [col][k] layout:
// btz[n][k<128]=gk[k][n], btz[n][128+k]=gr[k][n] (merged K=256 for z); btr same
// for r cols (+128). btcx[n][k]=gk[k][256+n]; btch[n][k]=gr[k][256+n].
__global__ void k_prep(const int* __restrict__ idx, const int* __restrict__ seqs,
                       const int* __restrict__ paths, int total,
                       const float* __restrict__ inputs,
                       const float* __restrict__ gk, const float* __restrict__ gr,
                       int* __restrict__ edge_map, f16* __restrict__ inx,
                       f16* __restrict__ btz, f16* __restrict__ btr,
                       f16* __restrict__ btcx, f16* __restrict__ btch) {
    const int i = blockIdx.x * 256 + threadIdx.x;   // grid covers NE*DIM = 524288
    if (i < total) edge_map[idx[i] * ML + seqs[i]] = paths[i];
    inx[i] = (f16)inputs[i];
    if (i < 16384) {
        const int n = i >> 7, k = i & 127;
        btz[n*256 + k]       = (f16)gk[k*384 + n];
        btz[n*256 + 128 + k] = (f16)gr[k*384 + n];
        btr[n*256 + k]       = (f16)gk[k*384 + 128 + n];
        btr[n*256 + 128 + k] = (f16)gr[k*384 + 128 + n];
        btcx[n*128 + k]      = (f16)gk[k*384 + 256 + n];
        btch[n*128 + k]      = (f16)gr[k*384 + 256 + n];
    }
}

// ---------------- fast activations ----------------
__device__ __forceinline__ float frcp(float x)  { return __builtin_amdgcn_rcpf(x); }
__device__ __forceinline__ float fsig(float x)  { return frcp(1.f + __expf(-x)); }
__device__ __forceinline__ float ftanh(float x) { float e = __expf(2.f * x); return 1.f - 2.f * frcp(e + 1.f); }

// ---------------- GRU forward (MFMA f16, TP=32) ----------------
// 512 thr = 8 waves; one 32-path tile per wg (2 independent row-tiles of 16).
// Wave w owns col-slice [16w,16w+16). Per step per wave: 48 mfma_f32_16x16x32_f16
// (per row-tile: Az K=256, Ar K=256, Ax/Ah K=128). B-fragments register-resident
// for the whole t-loop and SHARED by both row-tiles -> 2x work per step at same
// B-frag cost; the two row-tiles are independent until the barrier, doubling ILP
// to fill latency slots. Ping-pong H16, one lgkmcnt-only s_barrier per step.

__global__ __launch_bounds__(512, 2) void k_gru(
    const f16* __restrict__ inx, const int* __restrict__ lens,
    const f16* __restrict__ btz, const f16* __restrict__ btr,
    const f16* __restrict__ btcx, const f16* __restrict__ btch,
    const float* __restrict__ gb, const int* __restrict__ edge_map,
    const int* __restrict__ perm, f16* __restrict__ hs, float* __restrict__ last)
{
    __shared__ f16 H16[2][TP * DIM];   // 2 x 8 KB ping-pong, XOR-swizzled frag layout
    __shared__ int pgs[TP], lns[TP];

    const int tid  = threadIdx.x;
    const int lane = tid & 63;
    const int w    = tid >> 6;       // wave 0..7
    const int nw   = w * 16;         // column-slice base
    const int arow = lane & 15;      // A-row within row-tile, D-col (n offset)
    const int agrp = lane >> 4;      // 0..3
    const int d    = nw + arow;      // this lane's output column (0..127)

    if (tid < TP) { int pg = perm[blockIdx.x * TP + tid]; pgs[tid] = pg; lns[tid] = lens[pg]; }
    for (int i = tid; i < TP * DIM; i += 512) H16[0][i] = (f16)0.f;   // h0 = 0
    asm volatile("s_waitcnt lgkmcnt(0)" ::: "memory");
    __builtin_amdgcn_s_barrier();

    int tmax = 0;
    #pragma unroll
    for (int i = 0; i < TP; ++i) tmax = max(tmax, lns[i]);

    // B fragments (time-invariant) -> registers. 24 frags x 4 regs, shared by both tiles.
    f16x8 Bz[8], Br[8], Bx[4], Bh[4];
    {
        const int cb = d * 256 + agrp * 8;
        #pragma unroll
        for (int ks = 0; ks < 8; ++ks) {
            Bz[ks] = *(const f16x8*)(btz + cb + ks * 32);
            Br[ks] = *(const f16x8*)(btr + cb + ks * 32);
        }
        const int cc = d * 128 + agrp * 8;
        #pragma unroll
        for (int ks = 0; ks < 4; ++ks) {
            Bx[ks] = *(const f16x8*)(btcx + cc + ks * 32);
            Bh[ks] = *(const f16x8*)(btch + cc + ks * 32);
        }
    }

    // biases for column d (z,r halves pre-summed)
    const float bzc = gb[d]       + gb[384 + d];
    const float brc = gb[128 + d] + gb[512 + d];
    const float bxc = gb[256 + d];
    const float bhc = gb[640 + d];

    // per-lane state: row-tile 0 -> paths agrp*4+r, row-tile 1 -> 16+agrp*4+r
    float hold0[4] = {0.f,0.f,0.f,0.f}, hold1[4] = {0.f,0.f,0.f,0.f};
    int ln0[4], ln1[4], hsr0[4], hsr1[4], h16a0[4], h16a1[4], pg0[4], pg1[4];
    #pragma unroll
    for (int r = 0; r < 4; ++r) {
        const int pa = agrp * 4 + r;
        const int pb = 16 + pa;
        ln0[r] = lns[pa];            ln1[r] = lns[pb];
        pg0[r] = pgs[pa];            pg1[r] = pgs[pb];
        hsr0[r] = pgs[pa] * ML;      hsr1[r] = pgs[pb] * ML;
        h16a0[r] = pa * DIM + (((d >> 3) ^ (pa & 7)) * 8) + (d & 7);
        h16a1[r] = pb * DIM + (((d >> 3) ^ (pb & 7)) * 8) + (d & 7);
    }

    const int ep0 = pgs[arow] * ML;        // x-gather bases (A-frag row = arow)
    const int ep1 = pgs[16 + arow] * ML;

    // 2-deep prefetch pipeline per row-tile
    f16x8 xa0[4], xa1[4];
    int en0, en1;
    {
        const int e0 = edge_map[ep0] & (NE - 1);
        const int e1 = edge_map[ep1] & (NE - 1);
        const f16* xp0 = inx + e0 * DIM + agrp * 8;
        const f16* xp1 = inx + e1 * DIM + agrp * 8;
        #pragma unroll
        for (int ks = 0; ks < 4; ++ks) {
            xa0[ks] = *(const f16x8*)(xp0 + ks * 32);
            xa1[ks] = *(const f16x8*)(xp1 + ks * 32);
        }
        en0 = edge_map[ep0 + 1];
        en1 = edge_map[ep1 + 1];
    }

    for (int t = 0; t < tmax; ++t) {
        const f16* Hc = &H16[t & 1][0];
        f16*       Hn = &H16[(t & 1) ^ 1][0];

        // h fragments from LDS (chunk-XOR swizzle: conflict-free b128 reads)
        f16x8 ha0[4], ha1[4];
        #pragma unroll
        for (int ks = 0; ks < 4; ++ks) {
            const int chunk = (ks * 4 + agrp) ^ (arow & 7);
            ha0[ks] = *(const f16x8*)(Hc + arow * DIM + chunk * 8);
            ha1[ks] = *(const f16x8*)(Hc + (16 + arow) * DIM + chunk * 8);
        }

        f32x4 Az0 = {0.f,0.f,0.f,0.f}, Ar0 = {0.f,0.f,0.f,0.f};
        f32x4 Ax0 = {0.f,0.f,0.f,0.f}, Ah0 = {0.f,0.f,0.f,0.f};
        f32x4 Az1 = {0.f,0.f,0.f,0.f}, Ar1 = {0.f,0.f,0.f,0.f};
        f32x4 Ax1 = {0.f,0.f,0.f,0.f}, Ah1 = {0.f,0.f,0.f,0.f};
        #pragma unroll
        for (int ks = 0; ks < 4; ++ks) {
            Az0 = __builtin_amdgcn_mfma_f32_16x16x32_f16(xa0[ks], Bz[ks], Az0, 0, 0, 0);
            Az1 = __builtin_amdgcn_mfma_f32_16x16x32_f16(xa1[ks], Bz[ks], Az1, 0, 0, 0);
            Ar0 = __builtin_amdgcn_mfma_f32_16x16x32_f16(xa0[ks], Br[ks], Ar0, 0, 0, 0);
            Ar1 = __builtin_amdgcn_mfma_f32_16x16x32_f16(xa1[ks], Br[ks], Ar1, 0, 0, 0);
            Ax0 = __builtin_amdgcn_mfma_f32_16x16x32_f16(xa0[ks], Bx[ks], Ax0, 0, 0, 0);
            Ax1 = __builtin_amdgcn_mfma_f32_16x16x32_f16(xa1[ks], Bx[ks], Ax1, 0, 0, 0);
        }
        #pragma unroll
        for (int ks = 0; ks < 4; ++ks) {
            Az0 = __builtin_amdgcn_mfma_f32_16x16x32_f16(ha0[ks], Bz[4 + ks], Az0, 0, 0, 0);
            Az1 = __builtin_amdgcn_mfma_f32_16x16x32_f16(ha1[ks], Bz[4 + ks], Az1, 0, 0, 0);
            Ar0 = __builtin_amdgcn_mfma_f32_16x16x32_f16(ha0[ks], Br[4 + ks], Ar0, 0, 0, 0);
            Ar1 = __builtin_amdgcn_mfma_f32_16x16x32_f16(ha1[ks], Br[4 + ks], Ar1, 0, 0, 0);
            Ah0 = __builtin_amdgcn_mfma_f32_16x16x32_f16(ha0[ks], Bh[ks],     Ah0, 0, 0, 0);
            Ah1 = __builtin_amdgcn_mfma_f32_16x16x32_f16(ha1[ks], Bh[ks],     Ah1, 0, 0, 0);
        }

        // x for t+1 (edge ids loaded at t-1); edge ids for t+2 issued now
        {
            const int e0 = en0 & (NE - 1);   // mask: poison-safe
            const int e1 = en1 & (NE - 1);
            const f16* xp0 = inx + e0 * DIM + agrp * 8;
            const f16* xp1 = inx + e1 * DIM + agrp * 8;
            #pragma unroll
            for (int ks = 0; ks < 4; ++ks) {
                xa0[ks] = *(const f16x8*)(xp0 + ks * 32);
                xa1[ks] = *(const f16x8*)(xp1 + ks * 32);
            }
            const int tn2 = (t + 2 < ML) ? (t + 2) : (ML - 1);
            en0 = edge_map[ep0 + tn2];
            en1 = edge_map[ep1 + tn2];
        }

        // in-register GRU update, both row-tiles; branchless freeze past length
        #pragma unroll
        for (int r = 0; r < 4; ++r) {
            const float z  = fsig(Az0[r] + bzc);
            const float rg = fsig(Ar0[r] + brc);
            const float c  = ftanh(Ax0[r] + bxc + rg * (Ah0[r] + bhc));
            const float hn = z * hold0[r] + (1.f - z) * c;
            hold0[r] = (t < ln0[r]) ? hn : hold0[r];
            const f16 hv = (f16)hold0[r];
            Hn[h16a0[r]] = hv;
            hs[(hsr0[r] + t) * DIM + d] = hv;
        }
        #pragma unroll
        for (int r = 0; r < 4; ++r) {
            const float z  = fsig(Az1[r] + bzc);
            const float rg = fsig(Ar1[r] + brc);
            const float c  = ftanh(Ax1[r] + bxc + rg * (Ah1[r] + bhc));
            const float hn = z * hold1[r] + (1.f - z) * c;
            hold1[r] = (t < ln1[r]) ? hn : hold1[r];
            const f16 hv = (f16)hold1[r];
            Hn[h16a1[r]] = hv;
            hs[(hsr1[r] + t) * DIM + d] = hv;
        }

        // LDS-only hand-off: ds_writes visible, then barrier. Global ops float.
        asm volatile("s_waitcnt lgkmcnt(0)" ::: "memory");
        __builtin_amdgcn_s_barrier();
    }

    // last_state
    #pragma unroll
    for (int r = 0; r < 4; ++r) {
        last[pg0[r] * DIM + d] = hold0[r];
        last[pg1[r] * DIM + d] = hold1[r];
    }
}

// ---------------- q = last@Wq ; kq = Wk@q ----------------

__global__ __launch_bounds__(256, 2) void k_qkq(
    const float* __restrict__ last, const float* __restrict__ wq,
    const float* __restrict__ wk, float* __restrict__ kq)
{
    __shared__ float LT[DIM][64];
    __shared__ float QT[DIM][64];
    const int tid = threadIdx.x;
    const int pb = blockIdx.x * 64;
    {   // stage last (transposed)
        const int p  = tid >> 2;
        const int dd = (tid & 3) * 32;
        const float4* src = (const float4*)(last + (pb + p) * DIM + dd);
        #pragma unroll
        for (int q = 0; q < 8; ++q) {
            float4 v = src[q];
            LT[dd + q * 4 + 0][p] = v.x; LT[dd + q * 4 + 1][p] = v.y;
            LT[dd + q * 4 + 2][p] = v.z; LT[dd + q * 4 + 3][p] = v.w;
        }
    }
    __syncthreads();
    const int e0 = (tid & 63) * 2;
    const int p0 = (tid >> 6) * 16;
    float a0[16], a1[16];
    #pragma unroll
    for (int i = 0; i < 16; ++i) { a0[i] = a1[i] = 0.f; }
    for (int dd = 0; dd < DIM; ++dd) {
        const float2 ww = *(const float2*)(wq + dd * DIM + e0);
        #pragma unroll
        for (int i = 0; i < 16; ++i) {
            const float lv = LT[dd][p0 + i];
            a0[i] = fmaf(lv, ww.x, a0[i]);
            a1[i] = fmaf(lv, ww.y, a1[i]);
        }
    }
    #pragma unroll
    for (int i = 0; i < 16; ++i) { QT[e0][p0 + i] = a0[i]; QT[e0 + 1][p0 + i] = a1[i]; }
    __syncthreads();
    // kq[p][d] = sum_e wk[d][e] * q[p][e]
    float b0a[16], b1a[16];
    #pragma unroll
    for (int i = 0; i < 16; ++i) { b0a[i] = b1a[i] = 0.f; }
    for (int e = 0; e < DIM; ++e) {
        const float w0 = wk[e0 * DIM + e];
        const float w1 = wk[(e0 + 1) * DIM + e];
        #pragma unroll
        for (int i = 0; i < 16; ++i) {
            const float qv = QT[e][p0 + i];
            b0a[i] = fmaf(qv, w0, b0a[i]);
            b1a[i] = fmaf(qv, w1, b1a[i]);
        }
    }
    #pragma unroll
    for (int i = 0; i < 16; ++i) {
        float2 o; o.x = b0a[i]; o.y = b1a[i];
        *(float2*)(kq + (pb + p0 + i) * DIM + e0) = o;
    }
}

// ---------------- attention finalize ----------------
// context = (sum_l (h_l . kq) * h_l) @ Wv  — one wave per path; hs is f16.

__global__ __launch_bounds__(256) void k_attn(
    const f16* __restrict__ hs, const float* __restrict__ kq,
    const int* __restrict__ lens, const float* __restrict__ wv,
    float* __restrict__ out)
{
    __shared__ float ctx[4][DIM];
    const int tid  = threadIdx.x;
    const int wave = tid >> 6;
    const int lane = tid & 63;
    const int p    = blockIdx.x * 4 + wave;
    const int ln   = lens[p];
    const float2 kqv = *(const float2*)(kq + p * DIM + lane * 2);
    float c0 = 0.f, c1 = 0.f;
    for (int l = 0; l < ln; ++l) {
        const f16x2 h2 = *(const f16x2*)(hs + (p * ML + l) * DIM + lane * 2);
        const float hx = (float)h2.x, hy = (float)h2.y;
        float s = hx * kqv.x + hy * kqv.y;
        #pragma unroll
        for (int off = 32; off > 0; off >>= 1) s += __shfl_xor(s, off, 64);
        c0 = fmaf(s, hx, c0);
        c1 = fmaf(s, hy, c1);
    }
    ctx[wave][lane * 2]     = c0;
    ctx[wave][lane * 2 + 1] = c1;
    __syncthreads();
    const int ee = lane * 2;
    float o0 = 0.f, o1 = 0.f;
    for (int dd = 0; dd < DIM; ++dd) {
        const float cv = ctx[wave][dd];
        const float2 ww = *(const float2*)(wv + dd * DIM + ee);
        o0 = fmaf(cv, ww.x, o0);
        o1 = fmaf(cv, ww.y, o1);
    }
    float2 o; o.x = o0; o.y = o1;
    *(float2*)(out + p * DIM + ee) = o;
}

// ---------------- launch ----------------

extern "C" void kernel_launch(void* const* d_in, const int* in_sizes, int n_in,
                              void* d_out, int out_size, void* d_ws, size_t ws_size,
                              hipStream_t stream)
{
    const float* inputs = (const float*)d_in[0];
    const int*   paths  = (const int*)d_in[1];
    const int*   idx    = (const int*)d_in[2];
    const int*   seqs   = (const int*)d_in[3];
    const int*   lens   = (const int*)d_in[4];
    const float* gk     = (const float*)d_in[5];
    const float* gr     = (const float*)d_in[6];
    const float* gb     = (const float*)d_in[7];
    const float* wq     = (const float*)d_in[8];
    const float* wk     = (const float*)d_in[9];
    const float* wv     = (const float*)d_in[10];
    float* out = (float*)d_out;
    const int total = in_sizes[1];

    // workspace layout (~103 MB)
    float* last = (float*)d_ws;                        // [NP][DIM] f32
    float* kq   = last + (size_t)NP * DIM;             // [NP][DIM] f32
    f16*   hs   = (f16*)(kq + (size_t)NP * DIM);       // [NP][ML][DIM] f16
    f16*   inx  = hs + (size_t)NP * ML * DIM;          // [NE][DIM] f16
    f16*   btz  = inx + (size_t)NE * DIM;              // [128][256] f16
    f16*   btr  = btz + 128 * 256;                     // [128][256]
    f16*   btcx = btr + 128 * 256;                     // [128][128]
    f16*   btch = btcx + 128 * 128;                    // [128][128]
    int* edge_map = (int*)(btch + 128 * 128);          // [NP][ML]
    int* perm   = edge_map + NP * ML;                  // [NP]

    k_sort<<<1, 1024, 0, stream>>>(lens, perm);
    k_prep<<<(NE * DIM) / 256, 256, 0, stream>>>(idx, seqs, paths, total, inputs,
                                                 gk, gr, edge_map, inx,
                                                 btz, btr, btcx, btch);
    k_gru<<<NT, 512, 0, stream>>>(inx, lens, btz, btr, btcx, btch, gb, edge_map, perm, hs, last);
    k_qkq<<<NP / 64, 256, 0, stream>>>(last, wq, wk, kq);
    k_attn<<<NP / 4, 256, 0, stream>>>(hs, kq, lens, wv, out);
}

// Round 11
// 268.532 us; speedup vs baseline: 5.1436x; 1.0516x over previous
//
#include <hip/hip_runtime.h>
#include <cstdint>

#define NP 16384     // paths
#define NE 4096      // edges
#define DIM 128      // link/path dim
#define ML 20        // max len
#define TP 32        // paths per GRU tile (2 row-tiles of 16)
#define NT (NP/TP)   // 512 tiles

typedef _Float16 f16;
typedef _Float16 f16x8 __attribute__((ext_vector_type(8)));
typedef _Float16 f16x2 __attribute__((ext_vector_type(2)));
typedef float    f32x4 __attribute__((ext_vector_type(4)));

// ---------------- setup: wave-parallel counting sort (descending length) ----------------
__global__ __launch_bounds__(1024) void k_sort(const int* __restrict__ lens,
                                               int* __restrict__ perm) {
    __shared__ int wcnt[16][33];
    __shared__ int start[ML + 1];
    const int tid = threadIdx.x;
    const int wv  = tid >> 6;
    for (int i = tid; i < 16 * 33; i += 1024) ((int*)wcnt)[i] = 0;
    __syncthreads();
    #pragma unroll
    for (int k = 0; k < NP / 1024; ++k) {
        const int p = k * 1024 + tid;
        atomicAdd(&wcnt[wv][lens[p]], 1);   // wave-private: low contention
    }
    __syncthreads();
    if (tid == 0) {   // descending bin starts: longest first
        int s = 0;
        for (int i = ML; i >= 0; --i) {
            int c = 0;
            #pragma unroll
            for (int w2 = 0; w2 < 16; ++w2) c += wcnt[w2][i];
            start[i] = s; s += c;
        }
    }
    __syncthreads();
    if (tid <= ML) {  // per-bin: convert wave counts -> wave offsets
        int running = start[tid];
        #pragma unroll
        for (int w2 = 0; w2 < 16; ++w2) {
            int tmp = wcnt[w2][tid];
            wcnt[w2][tid] = running;
            running += tmp;
        }
    }
    __syncthreads();
    #pragma unroll
    for (int k = 0; k < NP / 1024; ++k) {
        const int p = k * 1024 + tid;
        int pos = atomicAdd(&wcnt[wv][lens[p]], 1);
        perm[pos] = p;   // order within bin nondeterministic; output invariant
    }
}

// ---------------- setup: fused edge scatter + f16 converts ----------------
// GRU weights to B-frag [col][k] layout (btz/btr merged K=256: x then h).
// wqt[n][k]=wq[k][n] (q=last@Wq); wkt[n][k]=wk[n][k] (kq=q@Wk^T).
__global__ void k_prep(const int* __restrict__ idx, const int* __restrict__ seqs,
                       const int* __restrict__ paths, int total,
                       const float* __restrict__ inputs,
                       const float* __restrict__ gk, const float* __restrict__ gr,
                       const float* __restrict__ wq, const float* __restrict__ wk,
                       int* __restrict__ edge_map, f16* __restrict__ inx,
                       f16* __restrict__ btz, f16* __restrict__ btr,
                       f16* __restrict__ btcx, f16* __restrict__ btch,
                       f16* __restrict__ wqt, f16* __restrict__ wkt) {
    const int i = blockIdx.x * 256 + threadIdx.x;   // grid covers NE*DIM = 524288
    if (i < total) edge_map[idx[i] * ML + seqs[i]] = paths[i];
    inx[i] = (f16)inputs[i];
    if (i < 16384) {
        const int n = i >> 7, k = i & 127;
        btz[n*256 + k]       = (f16)gk[k*384 + n];
        btz[n*256 + 128 + k] = (f16)gr[k*384 + n];
        btr[n*256 + k]       = (f16)gk[k*384 + 128 + n];
        btr[n*256 + 128 + k] = (f16)gr[k*384 + 128 + n];
        btcx[n*128 + k]      = (f16)gk[k*384 + 256 + n];
        btch[n*128 + k]      = (f16)gr[k*384 + 256 + n];
        wqt[n*128 + k]       = (f16)wq[k*128 + n];
        wkt[n*128 + k]       = (f16)wk[n*128 + k];
    }
}

// ---------------- fast activations ----------------
__device__ __forceinline__ float frcp(float x)  { return __builtin_amdgcn_rcpf(x); }
__device__ __forceinline__ float fsig(float x)  { return frcp(1.f + __expf(-x)); }
__device__ __forceinline__ float ftanh(float x) { float e = __expf(2.f * x); return 1.f - 2.f * frcp(e + 1.f); }

// ---------------- GRU forward (MFMA f16, TP=32, split-phase pipeline) ----------------
// 512 thr = 8 waves; wave w owns col-slice [16w,16w+16); 2 row-tiles of 16 paths.
// Loop split: post-barrier = {ds_read h, h-part MFMAs, update, ds_write}; tail
// (pre-barrier) = {x-part MFMAs for t+1 into fresh accs, xa reload} -> half the
// MFMA issue + all prefetch moved into the barrier-wait shadow; accs carried
// across the barrier in registers. Epilogue computes q=last@Wq and kq=q@Wk^T
// via MFMA using the dead ping-pong LDS buffer (replaces the k_qkq kernel).

__global__ __launch_bounds__(512, 2) void k_gru(
    const f16* __restrict__ inx, const int* __restrict__ lens,
    const f16* __restrict__ btz, const f16* __restrict__ btr,
    const f16* __restrict__ btcx, const f16* __restrict__ btch,
    const f16* __restrict__ wqt, const f16* __restrict__ wkt,
    const float* __restrict__ gb, const int* __restrict__ edge_map,
    const int* __restrict__ perm, f16* __restrict__ hs, float* __restrict__ kq)
{
    __shared__ f16 H16[2][TP * DIM];   // 2 x 8 KB ping-pong, XOR-swizzled frag layout
    __shared__ int pgs[TP], lns[TP];

    const int tid  = threadIdx.x;
    const int lane = tid & 63;
    const int w    = tid >> 6;       // wave 0..7
    const int nw   = w * 16;         // column-slice base
    const int arow = lane & 15;      // A-row within row-tile, D-col (n offset)
    const int agrp = lane >> 4;      // 0..3
    const int d    = nw + arow;      // this lane's output column (0..127)

    if (tid < TP) { int pg = perm[blockIdx.x * TP + tid]; pgs[tid] = pg; lns[tid] = lens[pg]; }
    for (int i = tid; i < TP * DIM; i += 512) H16[0][i] = (f16)0.f;   // h0 = 0
    asm volatile("s_waitcnt lgkmcnt(0)" ::: "memory");
    __builtin_amdgcn_s_barrier();

    int tmax = 0;
    #pragma unroll
    for (int i = 0; i < TP; ++i) tmax = max(tmax, lns[i]);

    // B fragments (time-invariant) -> registers; shared by both row-tiles.
    f16x8 Bz[8], Br[8], Bx[4], Bh[4];
    {
        const int cb = d * 256 + agrp * 8;
        #pragma unroll
        for (int ks = 0; ks < 8; ++ks) {
            Bz[ks] = *(const f16x8*)(btz + cb + ks * 32);
            Br[ks] = *(const f16x8*)(btr + cb + ks * 32);
        }
        const int cc = d * 128 + agrp * 8;
        #pragma unroll
        for (int ks = 0; ks < 4; ++ks) {
            Bx[ks] = *(const f16x8*)(btcx + cc + ks * 32);
            Bh[ks] = *(const f16x8*)(btch + cc + ks * 32);
        }
    }

    // biases for column d (z,r halves pre-summed)
    const float bzc = gb[d]       + gb[384 + d];
    const float brc = gb[128 + d] + gb[512 + d];
    const float bxc = gb[256 + d];
    const float bhc = gb[640 + d];

    // per-lane state: row-tile 0 -> paths agrp*4+r, row-tile 1 -> 16+agrp*4+r
    float hold0[4] = {0.f,0.f,0.f,0.f}, hold1[4] = {0.f,0.f,0.f,0.f};
    int ln0[4], ln1[4], hsr0[4], hsr1[4], h16a0[4], h16a1[4], pg0[4], pg1[4];
    #pragma unroll
    for (int r = 0; r < 4; ++r) {
        const int pa = agrp * 4 + r;
        const int pb = 16 + pa;
        ln0[r] = lns[pa];            ln1[r] = lns[pb];
        pg0[r] = pgs[pa];            pg1[r] = pgs[pb];
        hsr0[r] = pgs[pa] * ML;      hsr1[r] = pgs[pb] * ML;
        h16a0[r] = pa * DIM + (((d >> 3) ^ (pa & 7)) * 8) + (d & 7);
        h16a1[r] = pb * DIM + (((d >> 3) ^ (pb & 7)) * 8) + (d & 7);
    }

    const int ep0 = pgs[arow] * ML;        // x-gather bases (A-frag row = arow)
    const int ep1 = pgs[16 + arow] * ML;

    const f32x4 Z4 = {0.f, 0.f, 0.f, 0.f};
    f32x4 Az0, Ar0, Ax0, Az1, Ar1, Ax1;

    // prologue: xa(0), x-part accs for t=0, then xa(1) in flight
    f16x8 xa0[4], xa1[4];
    int en0, en1;
    {
        const int e0 = edge_map[ep0] & (NE - 1);
        const int e1 = edge_map[ep1] & (NE - 1);
        const f16* xp0 = inx + e0 * DIM + agrp * 8;
        const f16* xp1 = inx + e1 * DIM + agrp * 8;
        #pragma unroll
        for (int ks = 0; ks < 4; ++ks) {
            xa0[ks] = *(const f16x8*)(xp0 + ks * 32);
            xa1[ks] = *(const f16x8*)(xp1 + ks * 32);
        }
        en0 = edge_map[ep0 + 1];
        en1 = edge_map[ep1 + 1];
        Az0 = Z4; Ar0 = Z4; Ax0 = Z4; Az1 = Z4; Ar1 = Z4; Ax1 = Z4;
        #pragma unroll
        for (int ks = 0; ks < 4; ++ks) {
            Az0 = __builtin_amdgcn_mfma_f32_16x16x32_f16(xa0[ks], Bz[ks], Az0, 0, 0, 0);
            Az1 = __builtin_amdgcn_mfma_f32_16x16x32_f16(xa1[ks], Bz[ks], Az1, 0, 0, 0);
            Ar0 = __builtin_amdgcn_mfma_f32_16x16x32_f16(xa0[ks], Br[ks], Ar0, 0, 0, 0);
            Ar1 = __builtin_amdgcn_mfma_f32_16x16x32_f16(xa1[ks], Br[ks], Ar1, 0, 0, 0);
            Ax0 = __builtin_amdgcn_mfma_f32_16x16x32_f16(xa0[ks], Bx[ks], Ax0, 0, 0, 0);
            Ax1 = __builtin_amdgcn_mfma_f32_16x16x32_f16(xa1[ks], Bx[ks], Ax1, 0, 0, 0);
        }
        // xa <- x(1)
        const int f0 = en0 & (NE - 1);
        const int f1 = en1 & (NE - 1);
        const f16* yp0 = inx + f0 * DIM + agrp * 8;
        const f16* yp1 = inx + f1 * DIM + agrp * 8;
        #pragma unroll
        for (int ks = 0; ks < 4; ++ks) {
            xa0[ks] = *(const f16x8*)(yp0 + ks * 32);
            xa1[ks] = *(const f16x8*)(yp1 + ks * 32);
        }
        en0 = edge_map[ep0 + 2];
        en1 = edge_map[ep1 + 2];
    }

    for (int t = 0; t < tmax; ++t) {
        const f16* Hc = &H16[t & 1][0];
        f16*       Hn = &H16[(t & 1) ^ 1][0];

        // --- post-barrier phase: h-dependent work only ---
        f16x8 ha0[4], ha1[4];
        #pragma unroll
        for (int ks = 0; ks < 4; ++ks) {
            const int chunk = (ks * 4 + agrp) ^ (arow & 7);
            ha0[ks] = *(const f16x8*)(Hc + arow * DIM + chunk * 8);
            ha1[ks] = *(const f16x8*)(Hc + (16 + arow) * DIM + chunk * 8);
        }
        f32x4 Ah0 = Z4, Ah1 = Z4;
        #pragma unroll
        for (int ks = 0; ks < 4; ++ks) {
            Az0 = __builtin_amdgcn_mfma_f32_16x16x32_f16(ha0[ks], Bz[4 + ks], Az0, 0, 0, 0);
            Az1 = __builtin_amdgcn_mfma_f32_16x16x32_f16(ha1[ks], Bz[4 + ks], Az1, 0, 0, 0);
            Ar0 = __builtin_amdgcn_mfma_f32_16x16x32_f16(ha0[ks], Br[4 + ks], Ar0, 0, 0, 0);
            Ar1 = __builtin_amdgcn_mfma_f32_16x16x32_f16(ha1[ks], Br[4 + ks], Ar1, 0, 0, 0);
            Ah0 = __builtin_amdgcn_mfma_f32_16x16x32_f16(ha0[ks], Bh[ks],     Ah0, 0, 0, 0);
            Ah1 = __builtin_amdgcn_mfma_f32_16x16x32_f16(ha1[ks], Bh[ks],     Ah1, 0, 0, 0);
        }

        // update both row-tiles; LDS write first (critical), hs store after
        #pragma unroll
        for (int r = 0; r < 4; ++r) {
            const float z  = fsig(Az0[r] + bzc);
            const float rg = fsig(Ar0[r] + brc);
            const float c  = ftanh(Ax0[r] + bxc + rg * (Ah0[r] + bhc));
            const float hn = z * hold0[r] + (1.f - z) * c;
            hold0[r] = (t < ln0[r]) ? hn : hold0[r];
            const f16 hv = (f16)hold0[r];
            Hn[h16a0[r]] = hv;
            hs[(hsr0[r] + t) * DIM + d] = hv;
        }
        #pragma unroll
        for (int r = 0; r < 4; ++r) {
            const float z  = fsig(Az1[r] + bzc);
            const float rg = fsig(Ar1[r] + brc);
            const float c  = ftanh(Ax1[r] + bxc + rg * (Ah1[r] + bhc));
            const float hn = z * hold1[r] + (1.f - z) * c;
            hold1[r] = (t < ln1[r]) ? hn : hold1[r];
            const f16 hv = (f16)hold1[r];
            Hn[h16a1[r]] = hv;
            hs[(hsr1[r] + t) * DIM + d] = hv;
        }

        // --- tail (barrier shadow): x-part for t+1 into fresh accs + xa reload ---
        Az0 = Z4; Ar0 = Z4; Ax0 = Z4; Az1 = Z4; Ar1 = Z4; Ax1 = Z4;
        #pragma unroll
        for (int ks = 0; ks < 4; ++ks) {
            Az0 = __builtin_amdgcn_mfma_f32_16x16x32_f16(xa0[ks], Bz[ks], Az0, 0, 0, 0);
            Az1 = __builtin_amdgcn_mfma_f32_16x16x32_f16(xa1[ks], Bz[ks], Az1, 0, 0, 0);
            Ar0 = __builtin_amdgcn_mfma_f32_16x16x32_f16(xa0[ks], Br[ks], Ar0, 0, 0, 0);
            Ar1 = __builtin_amdgcn_mfma_f32_16x16x32_f16(xa1[ks], Br[ks], Ar1, 0, 0, 0);
            Ax0 = __builtin_amdgcn_mfma_f32_16x16x32_f16(xa0[ks], Bx[ks], Ax0, 0, 0, 0);
            Ax1 = __builtin_amdgcn_mfma_f32_16x16x32_f16(xa1[ks], Bx[ks], Ax1, 0, 0, 0);
        }
        {
            const int e0 = en0 & (NE - 1);   // mask: poison-safe
            const int e1 = en1 & (NE - 1);
            const f16* xp0 = inx + e0 * DIM + agrp * 8;
            const f16* xp1 = inx + e1 * DIM + agrp * 8;
            #pragma unroll
            for (int ks = 0; ks < 4; ++ks) {
                xa0[ks] = *(const f16x8*)(xp0 + ks * 32);
                xa1[ks] = *(const f16x8*)(xp1 + ks * 32);
            }
            const int tn3 = (t + 3 < ML) ? (t + 3) : (ML - 1);
            en0 = edge_map[ep0 + tn3];
            en1 = edge_map[ep1 + tn3];
        }

        asm volatile("s_waitcnt lgkmcnt(0)" ::: "memory");
        __builtin_amdgcn_s_barrier();
    }

    // ---------------- epilogue: q = last@Wq ; kq = q@Wk^T (replaces k_qkq) ----------------
    {
        const f16* Hf = &H16[tmax & 1][0];          // final h (frozen = last)
        f16*       Hq = &H16[(tmax & 1) ^ 1][0];    // dead buffer -> q staging

        f16x8 Bq[4], Bk[4];
        const int cw = d * 128 + agrp * 8;
        #pragma unroll
        for (int ks = 0; ks < 4; ++ks) {
            Bq[ks] = *(const f16x8*)(wqt + cw + ks * 32);
            Bk[ks] = *(const f16x8*)(wkt + cw + ks * 32);
        }

        f16x8 la0[4], la1[4];
        #pragma unroll
        for (int ks = 0; ks < 4; ++ks) {
            const int chunk = (ks * 4 + agrp) ^ (arow & 7);
            la0[ks] = *(const f16x8*)(Hf + arow * DIM + chunk * 8);
            la1[ks] = *(const f16x8*)(Hf + (16 + arow) * DIM + chunk * 8);
        }
        f32x4 Aq0 = Z4, Aq1 = Z4;
        #pragma unroll
        for (int ks = 0; ks < 4; ++ks) {
            Aq0 = __builtin_amdgcn_mfma_f32_16x16x32_f16(la0[ks], Bq[ks], Aq0, 0, 0, 0);
            Aq1 = __builtin_amdgcn_mfma_f32_16x16x32_f16(la1[ks], Bq[ks], Aq1, 0, 0, 0);
        }
        #pragma unroll
        for (int r = 0; r < 4; ++r) {
            Hq[h16a0[r]] = (f16)Aq0[r];
            Hq[h16a1[r]] = (f16)Aq1[r];
        }
        asm volatile("s_waitcnt lgkmcnt(0)" ::: "memory");
        __builtin_amdgcn_s_barrier();

        f16x8 qa0[4], qa1[4];
        #pragma unroll
        for (int ks = 0; ks < 4; ++ks) {
            const int chunk = (ks * 4 + agrp) ^ (arow & 7);
            qa0[ks] = *(const f16x8*)(Hq + arow * DIM + chunk * 8);
            qa1[ks] = *(const f16x8*)(Hq + (16 + arow) * DIM + chunk * 8);
        }
        f32x4 Ak0 = Z4, Ak1 = Z4;
        #pragma unroll
        for (int ks = 0; ks < 4; ++ks) {
            Ak0 = __builtin_amdgcn_mfma_f32_16x16x32_f16(qa0[ks], Bk[ks], Ak0, 0, 0, 0);
            Ak1 = __builtin_amdgcn_mfma_f32_16x16x32_f16(qa1[ks], Bk[ks], Ak1, 0, 0, 0);
        }
        #pragma unroll
        for (int r = 0; r < 4; ++r) {
            kq[pg0[r] * DIM + d] = Ak0[r];
            kq[pg1[r] * DIM + d] = Ak1[r];
        }
    }
}

// ---------------- attention finalize ----------------
// context = (sum_l (h_l . kq) * h_l) @ Wv  — one wave per path; hs is f16.

__global__ __launch_bounds__(256) void k_attn(
    const f16* __restrict__ hs, const float* __restrict__ kq,
    const int* __restrict__ lens, const float* __restrict__ wv,
    float* __restrict__ out)
{
    __shared__ float ctx[4][DIM];
    const int tid  = threadIdx.x;
    const int wave = tid >> 6;
    const int lane = tid & 63;
    const int p    = blockIdx.x * 4 + wave;
    const int ln   = lens[p];
    const float2 kqv = *(const float2*)(kq + p * DIM + lane * 2);
    float c0 = 0.f, c1 = 0.f;
    for (int l = 0; l < ln; ++l) {
        const f16x2 h2 = *(const f16x2*)(hs + (p * ML + l) * DIM + lane * 2);
        const float hx = (float)h2.x, hy = (float)h2.y;
        float s = hx * kqv.x + hy * kqv.y;
        #pragma unroll
        for (int off = 32; off > 0; off >>= 1) s += __shfl_xor(s, off, 64);
        c0 = fmaf(s, hx, c0);
        c1 = fmaf(s, hy, c1);
    }
    ctx[wave][lane * 2]     = c0;
    ctx[wave][lane * 2 + 1] = c1;
    __syncthreads();
    const int ee = lane * 2;
    float o0 = 0.f, o1 = 0.f;
    for (int dd = 0; dd < DIM; ++dd) {
        const float cv = ctx[wave][dd];
        const float2 ww = *(const float2*)(wv + dd * DIM + ee);
        o0 = fmaf(cv, ww.x, o0);
        o1 = fmaf(cv, ww.y, o1);
    }
    float2 o; o.x = o0; o.y = o1;
    *(float2*)(out + p * DIM + ee) = o;
}

// ---------------- launch ----------------

extern "C" void kernel_launch(void* const* d_in, const int* in_sizes, int n_in,
                              void* d_out, int out_size, void* d_ws, size_t ws_size,
                              hipStream_t stream)
{
    const float* inputs = (const float*)d_in[0];
    const int*   paths  = (const int*)d_in[1];
    const int*   idx    = (const int*)d_in[2];
    const int*   seqs   = (const int*)d_in[3];
    const int*   lens   = (const int*)d_in[4];
    const float* gk     = (const float*)d_in[5];
    const float* gr     = (const float*)d_in[6];
    const float* gb     = (const float*)d_in[7];
    const float* wq     = (const float*)d_in[8];
    const float* wk     = (const float*)d_in[9];
    const float* wv     = (const float*)d_in[10];
    float* out = (float*)d_out;
    const int total = in_sizes[1];

    // workspace layout (~92 MB)
    float* kq   = (float*)d_ws;                        // [NP][DIM] f32
    f16*   hs   = (f16*)(kq + (size_t)NP * DIM);       // [NP][ML][DIM] f16
    f16*   inx  = hs + (size_t)NP * ML * DIM;          // [NE][DIM] f16
    f16*   btz  = inx + (size_t)NE * DIM;              // [128][256] f16
    f16*   btr  = btz + 128 * 256;                     // [128][256]
    f16*   btcx = btr + 128 * 256;                     // [128][128]
    f16*   btch = btcx + 128 * 128;                    // [128][128]
    f16*   wqt  = btch + 128 * 128;                    // [128][128]
    f16*   wkt  = wqt + 128 * 128;                     // [128][128]
    int* edge_map = (int*)(wkt + 128 * 128);           // [NP][ML]
    int* perm   = edge_map + NP * ML;                  // [NP]

    k_sort<<<1, 1024, 0, stream>>>(lens, perm);
    k_prep<<<(NE * DIM) / 256, 256, 0, stream>>>(idx, seqs, paths, total, inputs,
                                                 gk, gr, wq, wk, edge_map, inx,
                                                 btz, btr, btcx, btch, wqt, wkt);
    k_gru<<<NT, 512, 0, stream>>>(inx, lens, btz, btr, btcx, btch, wqt, wkt,
                                  gb, edge_map, perm, hs, kq);
    k_attn<<<NP / 4, 256, 0, stream>>>(hs, kq, lens, wv, out);
}